// Round 2
// baseline (2839.438 us; speedup 1.0000x reference)
//
#include <hip/hip_runtime.h>
#include <stdint.h>

#define D_  480
#define H_  360
#define W_  32
#define N_  200000
#define DO_ 240
#define HO_ 180
#define WO_ 16
#define NCELL (DO_*HO_*WO_)     // 691,200
#define NVOX  (D_*H_*W_)        // 5,529,600
#define HBITS 19
#define HSZ   (1<<HBITS)
#define HMASK (HSZ-1)

// fallback persistent pool constants
#define PBZ_CELLS 32768
#define POOL_BLOCKS 512
#define POOL_WAVES (POOL_BLOCKS*4)
#define PB_PER_WAVE (PBZ_CELLS/POOL_WAVES)   // 16

__device__ __forceinline__ float bf2f(uint16_t u){
  uint32_t x=((uint32_t)u)<<16; return __builtin_bit_cast(float,x);
}
__device__ __forceinline__ uint16_t f2bf(float f){
  uint32_t x=__builtin_bit_cast(uint32_t,f);
  uint32_t r=x+0x7fffu+((x>>16)&1u);          // RNE
  return (uint16_t)(r>>16);
}
template<bool F32> __device__ __forceinline__ float ldv(const void* p,size_t i){
  if constexpr(F32) return ((const float*)p)[i];
  else return bf2f(((const uint16_t*)p)[i]);
}
template<bool F32> __device__ __forceinline__ void stv(void* p,size_t i,float v){
  if constexpr(F32) ((float*)p)[i]=v;
  else ((uint16_t*)p)[i]=f2bf(v);
}
// register-file broadcast: value of lane l (compile-time in unrolled loops)
__device__ __forceinline__ float rlane(float v,int l){
  return __builtin_bit_cast(float,
      __builtin_amdgcn_readlane(__builtin_bit_cast(int,v),l));
}
// dot: acc += sum_ci rlane(rv,ci) * wt[ci]; wt is per-lane contiguous f32.
// FP order: strictly ci-ascending single adds (matches previous passing kernel).
template<int CIN>
__device__ __forceinline__ void dotrow(float rv,const float* __restrict__ wt,float& acc){
  #pragma unroll
  for(int g=0;g<CIN/4;g++){
    float4 wv=((const float4*)wt)[g];
    acc += rlane(rv,4*g+0)*wv.x;
    acc += rlane(rv,4*g+1)*wv.y;
    acc += rlane(rv,4*g+2)*wv.z;
    acc += rlane(rv,4*g+3)*wv.w;
  }
}

__device__ __forceinline__ uint32_t hash0(int lin){
  return ((uint32_t)((uint32_t)lin*2654435761u)>>12)&HMASK;
}
__device__ __forceinline__ int hlookup(const int2* __restrict__ h,int lin){
  uint32_t s=hash0(lin);
  for(;;){ int2 kv=h[s]; if(kv.x==lin) return kv.y; if(kv.x<0) return -1; s=(s+1)&HMASK; }
}

// dtype sniff: flag[0]=1 iff inputs are f32. Also zeroes flag[1] (barrier cnt).
__global__ void k_sniff(const uint16_t* __restrict__ feats,int* __restrict__ flag){
  __shared__ int s;
  if(threadIdx.x==0) s=0;
  __syncthreads();
  int bad=0;
  for(int i=threadIdx.x;i<512;i+=256){
    int e=(feats[i]>>7)&0xff;
    bad += (e>=0x90)?1:0;
  }
  atomicAdd(&s,bad);
  __syncthreads();
  if(threadIdx.x==0){ flag[0]=(s>=8)?1:0; flag[1]=0; }
}

// ---------------- dense direct-index voxel table ----------------
__global__ void k_table_init(int* __restrict__ t){
  int i=blockIdx.x*256+threadIdx.x;
  if(i<NVOX/4) ((int4*)t)[i]=make_int4(-1,-1,-1,-1);
}
__global__ void k_table_build(const int4* __restrict__ coords,int* __restrict__ t){
  int i=blockIdx.x*256+threadIdx.x;
  if(i>=N_) return;
  int4 c=coords[i];                      // (b,z,y,x), b==0
  t[(c.y*H_+c.z)*W_+c.w]=i;
}

// ---------------- weight transpose: W[k][ci][co] -> WT[k][co][ci], f32 -----
template<int KK,int CIN>
__global__ void k_wt(const void* __restrict__ W,float* __restrict__ WT,
                     const int* __restrict__ flag){
  int i=blockIdx.x*256+threadIdx.x;
  if(i>=KK*CIN*64) return;
  float v = flag[0] ? ((const float*)W)[i] : bf2f(((const uint16_t*)W)[i]);
  int k=i/(CIN*64), r=i%(CIN*64);
  int ci=r>>6, co=r&63;
  WT[(size_t)k*CIN*64 + (size_t)co*CIN + ci]=v;
}

// ---------------- legacy hash (fallback path only) ----------------
__global__ void k_hash_init(int2* __restrict__ h){
  int i=blockIdx.x*256+threadIdx.x;
  if(i<HSZ) h[i]=make_int2(-1,-1);
}
__global__ void k_hash_build(const int4* __restrict__ coords,int2* __restrict__ h){
  int i=blockIdx.x*256+threadIdx.x;
  if(i>=N_) return;
  int4 c=coords[i];
  int lin=(c.y*H_+c.z)*W_+c.w;
  uint32_t s=hash0(lin);
  for(;;){
    int old=atomicCAS(&h[s].x,-1,lin);
    if(old==-1){ h[s].y=i; break; }
    s=(s+1)&HMASK;
  }
}

// =================================================================
// MAIN PATH: dense table + single-round cooperative row gather
// =================================================================

// subm conv: one voxel per wave, lane = out channel = row element.
// Row load: all lanes load row[lane] in ONE coalesced instruction; channel
// broadcast via v_readlane (register file, no extra memory rounds).
// SRC: 0=feats(input dtype) 1=buf0(bf16).  DST: 0=buf0 1=buf1 2=rA(out dtype)
template<int CIN,bool AXIS31,int SRC,int DST,bool RESID,bool F32>
__device__ __forceinline__ void convd_body(const void* __restrict__ feats,
                                           const int4* __restrict__ coords,
                                           const int* __restrict__ table,
                                           const float* __restrict__ WT,
                                           char* __restrict__ ob,
                                           uint16_t* __restrict__ buf0){
  constexpr size_t ESZ=F32?4:2;
  uint16_t* buf1=buf0+(size_t)N_*64;
  int wave=blockIdx.x*4+(threadIdx.x>>6);
  int lane=threadIdx.x&63;
  if(wave>=N_) return;
  int4 c=coords[wave];
  int z=c.y,y=c.z,x=c.w;
  int nidx=-1;
  if(lane<9){
    int d0=lane/3-1, dxo=lane%3-1;
    int nz=AXIS31? z+d0:z;
    int ny=AXIS31? y:y+d0;
    int nx=x+dxo;
    if(nz>=0&&nz<D_&&ny>=0&&ny<H_&&nx>=0&&nx<W_)
      nidx=table[(nz*H_+ny)*W_+nx];
  }
  unsigned long long m=__ballot(nidx>=0);
  float acc=0.f;
  while(m){
    int k0=__builtin_ctzll(m); m&=m-1;      // ascending k: ref FP order
    int i0=__shfl(nidx,k0);
    int k1=-1,i1=0;
    if(m){ k1=__builtin_ctzll(m); m&=m-1; i1=__shfl(nidx,k1); }
    float r0=0.f,r1=0.f;
    if constexpr(SRC==0){
      if(lane<CIN) r0=ldv<F32>(feats,(size_t)i0*CIN+lane);
      if(k1>=0 && lane<CIN) r1=ldv<F32>(feats,(size_t)i1*CIN+lane);
    }else{
      r0=bf2f(buf0[(size_t)i0*64+lane]);
      if(k1>=0) r1=bf2f(buf0[(size_t)i1*64+lane]);
    }
    dotrow<CIN>(r0,WT+(size_t)k0*CIN*64+(size_t)lane*CIN,acc);
    if(k1>=0) dotrow<CIN>(r1,WT+(size_t)k1*CIN*64+(size_t)lane*CIN,acc);
  }
  float v=acc>0.f? acc:0.01f*acc;
  if(RESID) v+=bf2f(buf1[(size_t)wave*64+lane]);
  size_t oi=(size_t)wave*64+lane;
  if(DST==0)      buf0[oi]=f2bf(v);
  else if(DST==1) buf1[oi]=f2bf(v);
  else            stv<F32>(ob+(size_t)NCELL*64*ESZ,oi,v);
}

template<int CIN,bool AXIS31,int SRC,int DST,bool RESID>
__global__ __launch_bounds__(256)
void k_convd(const void* feats,const int4* coords,const int* table,const float* WT,
             char* ob,uint16_t* buf0,const int* flag){
  if(flag[0]) convd_body<CIN,AXIS31,SRC,DST,RESID,true >(feats,coords,table,WT,ob,buf0);
  else        convd_body<CIN,AXIS31,SRC,DST,RESID,false>(feats,coords,table,WT,ob,buf0);
}

// pool: TWO cells per wave; lanes 0..26 / 32..58 probe the 27 taps of each
// cell in one table round. Per iteration one hit of each cell is processed,
// the two row loads overlapping. Rows gathered in ONE coalesced instruction.
template<bool F32>
__device__ __forceinline__ void poold_body(const int* __restrict__ table,
                                           const float* __restrict__ WpT,
                                           char* __restrict__ ob){
  constexpr size_t ESZ=F32?4:2;
  const char* rA=ob+(size_t)NCELL*64*ESZ;
  int wave=blockIdx.x*4+(threadIdx.x>>6);
  int lane=threadIdx.x&63;
  int cell0=wave*2;
  if(cell0>=NCELL) return;
  int half=lane>>5, l=lane&31;
  int cell=cell0+half;
  int ox=cell&(WO_-1);
  int t=cell>>4;                 // WO_ == 16
  int oy=t%HO_, oz=t/HO_;
  int nidx=-1;
  if(l<27){
    int kd=l/9, kh=(l/3)%3, kw=l%3;
    int z=2*oz+kd-1, y=2*oy+kh-1, x=2*ox+kw-1;
    if(z>=0&&z<D_&&y>=0&&y<H_&&x>=0&&x<W_)
      nidx=table[(z*H_+y)*W_+x];
  }
  unsigned long long m=__ballot(nidx>=0);
  unsigned int ma=(unsigned int)(m&0x07FFFFFFull);
  unsigned int mb=(unsigned int)((m>>32)&0x07FFFFFFull);
  float acc0=0.f, acc1=0.f;
  while(ma|mb){
    int ka=-1,kb=-1,ia=0,ib=0;
    if(ma){ ka=__builtin_ctz(ma); ma&=ma-1; ia=__shfl(nidx,ka); }
    if(mb){ kb=__builtin_ctz(mb); mb&=mb-1; ib=__shfl(nidx,32+kb); }
    float ra=0.f,rb=0.f;
    if(ka>=0) ra=ldv<F32>(rA,(size_t)ia*64+lane);
    if(kb>=0) rb=ldv<F32>(rA,(size_t)ib*64+lane);
    if(ka>=0) dotrow<64>(ra,WpT+(size_t)ka*4096+(size_t)lane*64,acc0);
    if(kb>=0) dotrow<64>(rb,WpT+(size_t)kb*4096+(size_t)lane*64,acc1);
  }
  stv<F32>(ob,(size_t)cell0*64+lane,acc0);
  stv<F32>(ob,((size_t)cell0+1)*64+lane,acc1);
}
__global__ __launch_bounds__(256)
void k_poold(const int* table,const float* WpT,char* ob,const int* flag){
  if(flag[0]) poold_body<true >(table,WpT,ob);
  else        poold_body<false>(table,WpT,ob);
}

// =================================================================
// FALLBACK PATH (ws too small): legacy hash-based kernels, unchanged
// =================================================================
template<int CIN,bool AXIS31,int SRC,int DST,bool RESID,bool WSBUF,bool F32>
__device__ __forceinline__ void conv_body(const void* __restrict__ feats,
                                          const int4* __restrict__ coords,
                                          const int2* __restrict__ hash,
                                          const void* __restrict__ Wk,
                                          char* __restrict__ ob,
                                          uint16_t* __restrict__ wsbuf0){
  constexpr size_t ESZ=F32?4:2;
  uint16_t* buf0 = WSBUF ? wsbuf0 : (uint16_t*)(ob+(size_t)PBZ_CELLS*64*ESZ);
  uint16_t* buf1 = buf0 + (size_t)N_*64;
  int wave=blockIdx.x*4+(threadIdx.x>>6);
  int lane=threadIdx.x&63;
  if(wave>=N_) return;
  int4 c=coords[wave];
  int z=c.y,y=c.z,x=c.w;
  float acc=0.f;
  #pragma unroll
  for(int k=0;k<9;k++){
    const int d0=k/3-1, dxo=k%3-1;
    int nz=AXIS31? z+d0:z;
    int ny=AXIS31? y:y+d0;
    int nx=x+dxo;
    int nidx=-1;
    if(nz>=0&&nz<D_&&ny>=0&&ny<H_&&nx>=0&&nx<W_)
      nidx=hlookup(hash,(nz*H_+ny)*W_+nx);
    nidx=__builtin_amdgcn_readfirstlane(nidx);
    if(nidx<0) continue;
    size_t fb=(size_t)nidx*CIN;
    size_t wb=(size_t)k*CIN*64+lane;
    #pragma unroll
    for(int ci=0;ci<CIN;ci+=2){
      float f0=(SRC==0)? ldv<F32>(feats,fb+ci)   : bf2f(buf0[fb+ci]);
      float f1=(SRC==0)? ldv<F32>(feats,fb+ci+1) : bf2f(buf0[fb+ci+1]);
      acc += f0*ldv<F32>(Wk,wb+(size_t)ci*64);
      acc += f1*ldv<F32>(Wk,wb+(size_t)(ci+1)*64);
    }
  }
  float v=acc>0.f? acc:0.01f*acc;
  if(RESID) v+=bf2f(buf1[(size_t)wave*64+lane]);
  size_t oi=(size_t)wave*64+lane;
  if(DST==0)      buf0[oi]=f2bf(v);
  else if(DST==1) buf1[oi]=f2bf(v);
  else            stv<F32>(ob+(size_t)NCELL*64*ESZ,oi,v);
}
template<int CIN,bool AXIS31,int SRC,int DST,bool RESID,bool WSBUF>
__global__ __launch_bounds__(256)
void k_conv(const void* feats,const int4* coords,const int2* hash,const void* Wk,
            char* ob,uint16_t* wsbuf0,const int* flag){
  if(flag[0]) conv_body<CIN,AXIS31,SRC,DST,RESID,WSBUF,true >(feats,coords,hash,Wk,ob,wsbuf0);
  else        conv_body<CIN,AXIS31,SRC,DST,RESID,WSBUF,false>(feats,coords,hash,Wk,ob,wsbuf0);
}
template<bool F32>
__device__ __forceinline__ float pool_cell_t(int cell,const void* __restrict__ rA,
    const int2* __restrict__ hash,const void* __restrict__ Wp,int lane){
  int ox=cell&(WO_-1);
  int t=cell>>4;
  int oy=t%HO_, oz=t/HO_;
  float acc=0.f;
  int k=0;
  for(int kd=0;kd<3;kd++)for(int kh=0;kh<3;kh++)for(int kw=0;kw<3;kw++,k++){
    int z=2*oz+kd-1, y=2*oy+kh-1, x=2*ox+kw-1;
    if(z<0||z>=D_||y<0||y>=H_||x<0||x>=W_) continue;
    int nidx=hlookup(hash,(z*H_+y)*W_+x);
    nidx=__builtin_amdgcn_readfirstlane(nidx);
    if(nidx<0) continue;
    size_t fb=(size_t)nidx*64;
    size_t wb=(size_t)k*4096+lane;
    #pragma unroll
    for(int ci=0;ci<64;ci+=2){
      acc+=ldv<F32>(rA,fb+ci)  *ldv<F32>(Wp,wb+(size_t)ci*64);
      acc+=ldv<F32>(rA,fb+ci+1)*ldv<F32>(Wp,wb+(size_t)(ci+1)*64);
    }
  }
  return acc;
}
template<bool F32>
__device__ __forceinline__ void pool_fb_body(const void* __restrict__ Wp,
                                             char* __restrict__ ob,
                                             int* __restrict__ cnt){
  constexpr size_t ESZ=F32?4:2;
  const int2* hash=(const int2*)ob;
  const void* rA=ob+(size_t)NCELL*64*ESZ;
  int w=blockIdx.x*4+(threadIdx.x>>6);
  int lane=threadIdx.x&63;
  for(int cell=PBZ_CELLS+w; cell<NCELL; cell+=POOL_WAVES)
    stv<F32>(ob,(size_t)cell*64+lane, pool_cell_t<F32>(cell,rA,hash,Wp,lane));
  float accb[PB_PER_WAVE];
  #pragma unroll
  for(int j=0;j<PB_PER_WAVE;j++)
    accb[j]=pool_cell_t<F32>(w*PB_PER_WAVE+j,rA,hash,Wp,lane);
  __syncthreads();
  if(threadIdx.x==0){
    __threadfence();
    atomicAdd(cnt,1);
    while(atomicAdd(cnt,0)<POOL_BLOCKS) __builtin_amdgcn_s_sleep(8);
  }
  __syncthreads();
  #pragma unroll
  for(int j=0;j<PB_PER_WAVE;j++)
    stv<F32>(ob,(size_t)(w*PB_PER_WAVE+j)*64+lane,accb[j]);
}
__global__ __launch_bounds__(256,2)
void k_pool_fb(const void* Wp,char* ob,int* cnt,const int* flag){
  if(flag[0]) pool_fb_body<true >(Wp,ob,cnt);
  else        pool_fb_body<false>(Wp,ob,cnt);
}

extern "C" void kernel_launch(void* const* d_in,const int* in_sizes,int n_in,
                              void* d_out,int out_size,void* d_ws,size_t ws_size,
                              hipStream_t stream){
  const uint16_t* feats_u16=(const uint16_t*)d_in[0];
  const void* feats=d_in[0];
  const int4* coords=(const int4*)d_in[1];
  const void* W1  =d_in[2];
  const void* W1_2=d_in[3];
  const void* W2  =d_in[4];
  const void* W3  =d_in[5];
  const void* Wp  =d_in[6];
  char* ob=(char*)d_out;
  int* flag=(int*)d_ws;                       // [0]=is_f32, [1]=barrier cnt

  // ws layout (main path):
  //   [0,256)                      flags
  //   +256: buf0 (N*64 bf16)       25.6 MB   } convs; dead before pool;
  //   +256+N*64*2: buf1            25.6 MB   } table rebuilt over buf0
  //   +256+2*N*64*2: WT region      884 KB   (f32 transposed weights)
  const size_t BUFS=(size_t)2*N_*64*2;
  const size_t WT_OFF=256+BUFS;
  const size_t WT_BYTES=(size_t)(9*64*32+9*64*64+9*64*32+9*64*64+27*64*64)*4;
  const size_t WS_NEED=WT_OFF+WT_BYTES;       // ~52.1 MB
  const bool ws_ok = ws_size >= WS_NEED;

  uint16_t* buf0_ws=(uint16_t*)((char*)d_ws+256);
  int*      tab_ws =(int*)((char*)d_ws+256);  // 22.1 MB over dead buf0 for pool
  int*      tab_ob =(int*)ob;                 // 22.1 MB inside pooled region
  float* w1t =(float*)((char*)d_ws+WT_OFF);
  float* w12t=w1t +9*64*32;
  float* w2t =w12t+9*64*64;
  float* w3t =w2t +9*64*32;
  float* wpt =w3t +9*64*64;

  k_sniff<<<1,256,0,stream>>>(feats_u16,flag);

  if(ws_ok){
    k_table_init <<<NVOX/4/256,256,0,stream>>>(tab_ob);
    k_table_build<<<(N_+255)/256,256,0,stream>>>(coords,tab_ob);
    k_wt< 9,32><<<( 9*32*64+255)/256,256,0,stream>>>(W1  ,w1t ,flag);
    k_wt< 9,64><<<( 9*64*64+255)/256,256,0,stream>>>(W1_2,w12t,flag);
    k_wt< 9,32><<<( 9*32*64+255)/256,256,0,stream>>>(W2  ,w2t ,flag);
    k_wt< 9,64><<<( 9*64*64+255)/256,256,0,stream>>>(W3  ,w3t ,flag);
    k_wt<27,64><<<(27*64*64+255)/256,256,0,stream>>>(Wp  ,wpt ,flag);
    k_convd<32,true ,0,0,false><<<N_/4,256,0,stream>>>(feats,coords,tab_ob,w1t ,ob,buf0_ws,flag);
    k_convd<64,false,1,1,false><<<N_/4,256,0,stream>>>(feats,coords,tab_ob,w12t,ob,buf0_ws,flag);
    k_convd<32,false,0,0,false><<<N_/4,256,0,stream>>>(feats,coords,tab_ob,w2t ,ob,buf0_ws,flag);
    k_convd<64,true ,1,2,true ><<<N_/4,256,0,stream>>>(feats,coords,tab_ob,w3t ,ob,buf0_ws,flag);
    // bufs dead now; rebuild table in ws so pool output can't clobber it
    k_table_init <<<NVOX/4/256,256,0,stream>>>(tab_ws);
    k_table_build<<<(N_+255)/256,256,0,stream>>>(coords,tab_ws);
    k_poold<<<NCELL/8,256,0,stream>>>(tab_ws,wpt,ob,flag);
  }else{
    int2* hash=(int2*)ob;
    k_hash_init<<<(HSZ+255)/256,256,0,stream>>>(hash);
    k_hash_build<<<(N_+255)/256,256,0,stream>>>(coords,hash);
    k_conv<32,true ,0,0,false,false><<<N_/4,256,0,stream>>>(feats,coords,hash,W1  ,ob,nullptr,flag);
    k_conv<64,false,1,1,false,false><<<N_/4,256,0,stream>>>(feats,coords,hash,W1_2,ob,nullptr,flag);
    k_conv<32,false,0,0,false,false><<<N_/4,256,0,stream>>>(feats,coords,hash,W2  ,ob,nullptr,flag);
    k_conv<64,true ,1,2,true ,false><<<N_/4,256,0,stream>>>(feats,coords,hash,W3  ,ob,nullptr,flag);
    k_pool_fb<<<POOL_BLOCKS,256,0,stream>>>(Wp,ob,flag+1,flag);
  }
}

// Round 3
// 2295.074 us; speedup vs baseline: 1.2372x; 1.2372x over previous
//
#include <hip/hip_runtime.h>
#include <stdint.h>

#define D_  480
#define H_  360
#define W_  32
#define N_  200000
#define DO_ 240
#define HO_ 180
#define WO_ 16
#define NCELL (DO_*HO_*WO_)     // 691,200
#define NVOX  (D_*H_*W_)        // 5,529,600
#define HBITS 19
#define HSZ   (1<<HBITS)
#define HMASK (HSZ-1)
#define CAPC 16384              // per off-center conv tap (expect ~7.2k)
#define CAPP 32768              // per pool tap (expect ~25k)

// fallback persistent pool constants
#define PBZ_CELLS 32768
#define POOL_BLOCKS 512
#define POOL_WAVES (POOL_BLOCKS*4)
#define PB_PER_WAVE (PBZ_CELLS/POOL_WAVES)   // 16

__device__ __forceinline__ float bf2f(uint16_t u){
  uint32_t x=((uint32_t)u)<<16; return __builtin_bit_cast(float,x);
}
__device__ __forceinline__ uint16_t f2bf(float f){
  uint32_t x=__builtin_bit_cast(uint32_t,f);
  uint32_t r=x+0x7fffu+((x>>16)&1u);          // RNE
  return (uint16_t)(r>>16);
}
template<bool F32> __device__ __forceinline__ float ldv(const void* p,size_t i){
  if constexpr(F32) return ((const float*)p)[i];
  else return bf2f(((const uint16_t*)p)[i]);
}
template<bool F32> __device__ __forceinline__ void stv(void* p,size_t i,float v){
  if constexpr(F32) ((float*)p)[i]=v;
  else ((uint16_t*)p)[i]=f2bf(v);
}
// broadcast-load 8 consecutive values -> f32[8] (bf16 path)
template<bool F32> __device__ __forceinline__ void ld8(const void* p,size_t base,float* v){
  if constexpr(F32){
    const float4* q=(const float4*)((const float*)p+base);
    float4 a=q[0], b=q[1];
    v[0]=a.x;v[1]=a.y;v[2]=a.z;v[3]=a.w;
    v[4]=b.x;v[5]=b.y;v[6]=b.z;v[7]=b.w;
  }else{
    const uint4* q=(const uint4*)((const uint16_t*)p+base);
    uint4 a=q[0];
    v[0]=bf2f((uint16_t)(a.x&0xffffu)); v[1]=bf2f((uint16_t)(a.x>>16));
    v[2]=bf2f((uint16_t)(a.y&0xffffu)); v[3]=bf2f((uint16_t)(a.y>>16));
    v[4]=bf2f((uint16_t)(a.z&0xffffu)); v[5]=bf2f((uint16_t)(a.z>>16));
    v[6]=bf2f((uint16_t)(a.w&0xffffu)); v[7]=bf2f((uint16_t)(a.w>>16));
  }
}
// register-file broadcast (ci is compile-time in unrolled loops)
__device__ __forceinline__ float rlane(float v,int l){
  return __builtin_bit_cast(float,
      __builtin_amdgcn_readlane(__builtin_bit_cast(int,v),l));
}

__device__ __forceinline__ uint32_t hash0(int lin){
  return ((uint32_t)((uint32_t)lin*2654435761u)>>12)&HMASK;
}
__device__ __forceinline__ int hlookup(const int2* __restrict__ h,int lin){
  uint32_t s=hash0(lin);
  for(;;){ int2 kv=h[s]; if(kv.x==lin) return kv.y; if(kv.x<0) return -1; s=(s+1)&HMASK; }
}

// dtype sniff: flag[0]=1 iff inputs are f32. Zeroes flag[1] + 45 list counters.
__global__ void k_sniff(const uint16_t* __restrict__ feats,int* __restrict__ flag){
  __shared__ int s;
  if(threadIdx.x==0) s=0;
  __syncthreads();
  int bad=0;
  for(int i=threadIdx.x;i<512;i+=256){
    int e=(feats[i]>>7)&0xff;
    bad += (e>=0x90)?1:0;
  }
  atomicAdd(&s,bad);
  if(threadIdx.x<45) flag[32+threadIdx.x]=0;   // counters live at byte 128
  __syncthreads();
  if(threadIdx.x==0){ flag[0]=(s>=8)?1:0; flag[1]=0; }
}

// ---------------- dense direct-index voxel table (lives in ws) ----------------
__global__ void k_table_init(int* __restrict__ t){
  int i=blockIdx.x*256+threadIdx.x;
  if(i<NVOX/4) ((int4*)t)[i]=make_int4(-1,-1,-1,-1);
}
__global__ void k_table_build(const int4* __restrict__ coords,int* __restrict__ t){
  int i=blockIdx.x*256+threadIdx.x;
  if(i>=N_) return;
  int4 c=coords[i];                      // (b,z,y,x), b==0
  t[(c.y*H_+c.z)*W_+c.w]=i;
}

// ---------------- legacy hash (fallback path only) ----------------
__global__ void k_hash_init(int2* __restrict__ h){
  int i=blockIdx.x*256+threadIdx.x;
  if(i<HSZ) h[i]=make_int2(-1,-1);
}
__global__ void k_hash_build(const int4* __restrict__ coords,int2* __restrict__ h){
  int i=blockIdx.x*256+threadIdx.x;
  if(i>=N_) return;
  int4 c=coords[i];
  int lin=(c.y*H_+c.z)*W_+c.w;
  uint32_t s=hash0(lin);
  for(;;){
    int old=atomicCAS(&h[s].x,-1,lin);
    if(old==-1){ h[s].y=i; break; }
    s=(s+1)&HMASK;
  }
}

// =================================================================
// MAIN F32 PATH: k-grouped pair lists + register-resident weights
// =================================================================

// wave-aggregated list append (one atomic per wave per tap)
__device__ __forceinline__ void wappend(int2* __restrict__ lst,int* __restrict__ cnt,
                                        int cap,int a,int b,bool want,int lane){
  unsigned long long m=__ballot(want);
  if(m==0ull) return;
  int first=__builtin_ctzll(m);
  int base=0;
  if(lane==first) base=atomicAdd(cnt,__popcll(m));
  base=__shfl(base,first);
  if(want){
    int pref=__popcll(m&((1ull<<lane)-1ull));
    int pos=base+pref;
    if(pos<cap) lst[pos]=make_int2(a,b);
  }
}

// conv pair lists for both offset patterns (off-center taps only; k=4 is identity)
__global__ __launch_bounds__(256)
void k_build_conv(const int4* __restrict__ coords,const int* __restrict__ table,
                  int2* __restrict__ listA,int2* __restrict__ listB,
                  int* __restrict__ cntA,int* __restrict__ cntB,
                  const int* __restrict__ flag){
  if(!flag[0]) return;
  int i=blockIdx.x*256+threadIdx.x;
  bool valid=i<N_;
  int4 c = valid? coords[i] : make_int4(0,0,0,0);
  int z=c.y,y=c.z,x=c.w;
  int lane=threadIdx.x&63;
  #pragma unroll
  for(int k=0;k<9;k++){
    if(k==4) continue;
    int d0=k/3-1, dx=k%3-1;
    { // pattern A (OFF_31): (dz,0,dx)
      int nz=z+d0, nx=x+dx;
      int src=-1;
      if(valid && nz>=0&&nz<D_&&nx>=0&&nx<W_) src=table[(nz*H_+y)*W_+nx];
      wappend(listA+(size_t)k*CAPC,&cntA[k],CAPC,i,src,src>=0,lane);
    }
    { // pattern B (OFF_13): (0,dy,dx)
      int ny=y+d0, nx=x+dx;
      int src=-1;
      if(valid && ny>=0&&ny<H_&&nx>=0&&nx<W_) src=table[(z*H_+ny)*W_+nx];
      wappend(listB+(size_t)k*CAPC,&cntB[k],CAPC,i,src,src>=0,lane);
    }
  }
}

// pool pair lists: voxel i contributes to cell (oz,oy,ox) at tap k iff parity+range ok
__global__ __launch_bounds__(256)
void k_build_pool(const int4* __restrict__ coords,int2* __restrict__ listP,
                  int* __restrict__ cntP,const int* __restrict__ flag){
  if(!flag[0]) return;
  int i=blockIdx.x*256+threadIdx.x;
  bool valid=i<N_;
  int4 c = valid? coords[i] : make_int4(0,0,0,0);
  int z=c.y,y=c.z,x=c.w;
  int lane=threadIdx.x&63;
  #pragma unroll
  for(int kd=0;kd<3;kd++)
  #pragma unroll
  for(int kh=0;kh<3;kh++)
  #pragma unroll
  for(int kw=0;kw<3;kw++){
    int k=kd*9+kh*3+kw;
    int tz=z+1-kd, ty=y+1-kh, tx=x+1-kw;
    bool ok = valid && !(tz&1)&&!(ty&1)&&!(tx&1);
    int oz=tz>>1, oy=ty>>1, ox=tx>>1;
    ok = ok && oz>=0&&oz<DO_&&oy>=0&&oy<HO_&&ox>=0&&ox<WO_;
    int cell = ok? ((oz*HO_+oy)*WO_+ox) : -1;
    wappend(listP+(size_t)k*CAPP,&cntP[k],CAPP,cell,i,ok,lane);
  }
}

// center tap (k=4): dst row p = src row p @ W[4]; bijection -> plain store.
// lane = cout; weights register-resident; 4 rows interleaved for ILP.
template<int CIN>
__global__ __launch_bounds__(256)
void k_center(const float* __restrict__ src,const float* __restrict__ Wl,
              float* __restrict__ dst,const int* __restrict__ flag){
  if(!flag[0]) return;
  int wave=blockIdx.x*4+(threadIdx.x>>6);
  int lane=threadIdx.x&63;
  int p0=wave*4;                        // N_ % 16 == 0 -> exact
  if(p0>=N_) return;
  float w[CIN];
  #pragma unroll
  for(int ci=0;ci<CIN;ci++) w[ci]=Wl[(size_t)4*CIN*64+(size_t)ci*64+lane];
  int li=(CIN==64)? lane : (lane&31);
  float r0=src[(size_t)(p0+0)*CIN+li];
  float r1=src[(size_t)(p0+1)*CIN+li];
  float r2=src[(size_t)(p0+2)*CIN+li];
  float r3=src[(size_t)(p0+3)*CIN+li];
  float a0=0.f,a1=0.f,a2=0.f,a3=0.f;
  #pragma unroll
  for(int ci=0;ci<CIN;ci++){
    float wc=w[ci];
    a0+=rlane(r0,ci)*wc; a1+=rlane(r1,ci)*wc;
    a2+=rlane(r2,ci)*wc; a3+=rlane(r3,ci)*wc;
  }
  dst[(size_t)(p0+0)*64+lane]=a0;
  dst[(size_t)(p0+1)*64+lane]=a1;
  dst[(size_t)(p0+2)*64+lane]=a2;
  dst[(size_t)(p0+3)*64+lane]=a3;
}

// off-center conv taps: stream (dst,src) pairs of tap g, atomicAdd into dst rows
template<int CIN>
__global__ __launch_bounds__(256)
void k_off(const float* __restrict__ src,const float* __restrict__ Wl,
           const int2* __restrict__ lists,const int* __restrict__ cnt,
           float* __restrict__ dst,const int* __restrict__ flag){
  if(!flag[0]) return;
  int g=blockIdx.y;
  if(g==4) return;
  int n=min(cnt[g],CAPC);
  const int2* lst=lists+(size_t)g*CAPC;
  int wave=blockIdx.x*4+(threadIdx.x>>6);
  int lane=threadIdx.x&63;
  float w[CIN];
  #pragma unroll
  for(int ci=0;ci<CIN;ci++) w[ci]=Wl[(size_t)g*CIN*64+(size_t)ci*64+lane];
  int nw=gridDim.x*4;
  int li=(CIN==64)? lane : (lane&31);
  for(int p=wave;p<n;p+=nw){
    int2 pr=lst[p];                     // (dst, src)
    float r=src[(size_t)pr.y*CIN+li];
    float a=0.f;
    #pragma unroll
    for(int ci=0;ci<CIN;ci++) a+=rlane(r,ci)*w[ci];
    atomicAdd(&dst[(size_t)pr.x*64+lane],a);
  }
}

// pool stream: tap g weights resident; 4 (cell,voxel) pairs in flight
__global__ __launch_bounds__(256)
void k_pools(const float* __restrict__ rAp,const float* __restrict__ Wp,
             const int2* __restrict__ listP,const int* __restrict__ cntP,
             float* __restrict__ out,const int* __restrict__ flag){
  if(!flag[0]) return;
  int g=blockIdx.y;
  int n=min(cntP[g],CAPP);
  const int2* lst=listP+(size_t)g*CAPP;
  int wave=blockIdx.x*4+(threadIdx.x>>6);
  int lane=threadIdx.x&63;
  float w[64];
  #pragma unroll
  for(int ci=0;ci<64;ci++) w[ci]=Wp[(size_t)g*4096+(size_t)ci*64+lane];
  int nw=gridDim.x*4;
  for(int p0=wave*4;p0<n;p0+=nw*4){
    int pB=p0+1,pC=p0+2,pD=p0+3;
    bool vB=pB<n, vC=pC<n, vD=pD<n;
    int2 qA=lst[p0];
    int2 qB=vB?lst[pB]:qA;
    int2 qC=vC?lst[pC]:qA;
    int2 qD=vD?lst[pD]:qA;
    float rA_=rAp[(size_t)qA.y*64+lane];
    float rB_=rAp[(size_t)qB.y*64+lane];
    float rC_=rAp[(size_t)qC.y*64+lane];
    float rD_=rAp[(size_t)qD.y*64+lane];
    float aA=0.f,aB=0.f,aC=0.f,aD=0.f;
    #pragma unroll
    for(int ci=0;ci<64;ci++){
      float wc=w[ci];
      aA+=rlane(rA_,ci)*wc;
      aB+=rlane(rB_,ci)*wc;
      aC+=rlane(rC_,ci)*wc;
      aD+=rlane(rD_,ci)*wc;
    }
    atomicAdd(&out[(size_t)qA.x*64+lane],aA);
    if(vB) atomicAdd(&out[(size_t)qB.x*64+lane],aB);
    if(vC) atomicAdd(&out[(size_t)qC.x*64+lane],aC);
    if(vD) atomicAdd(&out[(size_t)qD.x*64+lane],aD);
  }
}

__device__ __forceinline__ float lk(float v){ return v>0.f? v:0.01f*v; }

__global__ __launch_bounds__(256)
void k_act(float* __restrict__ buf,const int* __restrict__ flag){
  if(!flag[0]) return;
  size_t n=(size_t)N_*64;
  size_t stride=(size_t)gridDim.x*1024;
  for(size_t i=((size_t)blockIdx.x*256+threadIdx.x)*4;i<n;i+=stride){
    float4 v=*(float4*)(buf+i);
    v.x=lk(v.x); v.y=lk(v.y); v.z=lk(v.z); v.w=lk(v.w);
    *(float4*)(buf+i)=v;
  }
}
__global__ __launch_bounds__(256)
void k_act_resid(float* __restrict__ r,const float* __restrict__ sc,
                 const int* __restrict__ flag){
  if(!flag[0]) return;
  size_t n=(size_t)N_*64;
  size_t stride=(size_t)gridDim.x*1024;
  for(size_t i=((size_t)blockIdx.x*256+threadIdx.x)*4;i<n;i+=stride){
    float4 v=*(float4*)(r+i);
    float4 s=*(const float4*)(sc+i);
    v.x=lk(v.x)+s.x; v.y=lk(v.y)+s.y; v.z=lk(v.z)+s.z; v.w=lk(v.w)+s.w;
    *(float4*)(r+i)=v;
  }
}
__global__ __launch_bounds__(256)
void k_zero(float* __restrict__ out,const int* __restrict__ flag){
  if(!flag[0]) return;
  size_t n=(size_t)NCELL*64;
  size_t stride=(size_t)gridDim.x*1024;
  float4 z=make_float4(0.f,0.f,0.f,0.f);
  for(size_t i=((size_t)blockIdx.x*256+threadIdx.x)*4;i<n;i+=stride)
    *(float4*)(out+i)=z;
}

// =================================================================
// BF16 MAIN PATH (flag==0): verified R1 gather kernels, bufs in ob scratch
// =================================================================
template<int CIN,bool AXIS31,int SRC,int DST,bool RESID>
__global__ __launch_bounds__(256)
void k_convb(const void* __restrict__ feats,const int4* __restrict__ coords,
             const int* __restrict__ table,const void* __restrict__ Wk,
             char* __restrict__ ob,const int* __restrict__ flag){
  if(flag[0]) return;
  uint16_t* buf0=(uint16_t*)ob;
  uint16_t* buf1=buf0+(size_t)N_*64;
  int wave=blockIdx.x*4+(threadIdx.x>>6);
  int lane=threadIdx.x&63;
  if(wave>=N_) return;
  int4 c=coords[wave];
  int z=c.y,y=c.z,x=c.w;
  int nidx=-1;
  if(lane<9){
    int d0=lane/3-1, dxo=lane%3-1;
    int nz=AXIS31? z+d0:z;
    int ny=AXIS31? y:y+d0;
    int nx=x+dxo;
    if(nz>=0&&nz<D_&&ny>=0&&ny<H_&&nx>=0&&nx<W_)
      nidx=table[(nz*H_+ny)*W_+nx];
  }
  unsigned long long m=__ballot(nidx>=0);
  float acc=0.f;
  while(m){
    int k=__builtin_ctzll(m); m&=m-1;
    int idx=__shfl(nidx,k);
    size_t fb=(size_t)idx*CIN;
    size_t wb=(size_t)k*CIN*64+lane;
    #pragma unroll
    for(int g=0;g<CIN/8;g++){
      float f[8];
      if(SRC==0) ld8<false>(feats,fb+(size_t)8*g,f);
      else       ld8<false>(buf0 ,fb+(size_t)8*g,f);
      #pragma unroll
      for(int j=0;j<8;j++)
        acc+=f[j]*ldv<false>(Wk,wb+(size_t)(8*g+j)*64);
    }
  }
  float v=acc>0.f? acc:0.01f*acc;
  if(RESID) v+=bf2f(buf1[(size_t)wave*64+lane]);
  size_t oi=(size_t)wave*64+lane;
  if(DST==0)      buf0[oi]=f2bf(v);
  else if(DST==1) buf1[oi]=f2bf(v);
  else            stv<false>(ob+(size_t)NCELL*64*2,oi,v);
}

__global__ __launch_bounds__(256)
void k_poolb(const int* __restrict__ table,const void* __restrict__ Wp,
             char* __restrict__ ob,const int* __restrict__ flag){
  if(flag[0]) return;
  const char* rAp=ob+(size_t)NCELL*64*2;
  int wave=blockIdx.x*4+(threadIdx.x>>6);
  int lane=threadIdx.x&63;
  int cell0=wave*2;
  if(cell0>=NCELL) return;
  int half=lane>>5, l=lane&31;
  int cell=cell0+half;
  int ox=cell&(WO_-1);
  int t=cell>>4;
  int oy=t%HO_, oz=t/HO_;
  int nidx=-1;
  if(l<27){
    int kd=l/9, kh=(l/3)%3, kw=l%3;
    int z=2*oz+kd-1, y=2*oy+kh-1, x=2*ox+kw-1;
    if(z>=0&&z<D_&&y>=0&&y<H_&&x>=0&&x<W_)
      nidx=table[(z*H_+y)*W_+x];
  }
  unsigned long long m=__ballot(nidx>=0);
  unsigned int ma=(unsigned int)(m&0x07FFFFFFull);
  unsigned int mb=(unsigned int)((m>>32)&0x07FFFFFFull);
  float acc0=0.f, acc1=0.f;
  while(ma|mb){
    int ka=-1,kb=-1,ia=0,ib=0;
    if(ma){ ka=__builtin_ctz(ma); ma&=ma-1; ia=__shfl(nidx,ka); }
    if(mb){ kb=__builtin_ctz(mb); mb&=mb-1; ib=__shfl(nidx,32+kb); }
    if(ka>=0){
      size_t fb=(size_t)ia*64, wb=(size_t)ka*4096+lane;
      #pragma unroll
      for(int g=0;g<8;g++){
        float f[8]; ld8<false>(rAp,fb+(size_t)8*g,f);
        #pragma unroll
        for(int j=0;j<8;j++) acc0+=f[j]*ldv<false>(Wp,wb+(size_t)(8*g+j)*64);
      }
    }
    if(kb>=0){
      size_t fb=(size_t)ib*64, wb=(size_t)kb*4096+lane;
      #pragma unroll
      for(int g=0;g<8;g++){
        float f[8]; ld8<false>(rAp,fb+(size_t)8*g,f);
        #pragma unroll
        for(int j=0;j<8;j++) acc1+=f[j]*ldv<false>(Wp,wb+(size_t)(8*g+j)*64);
      }
    }
  }
  stv<false>(ob,(size_t)cell0*64+lane,acc0);
  stv<false>(ob,((size_t)cell0+1)*64+lane,acc1);
}

// =================================================================
// FALLBACK PATH (ws too small): legacy hash-based kernels, unchanged
// =================================================================
template<int CIN,bool AXIS31,int SRC,int DST,bool RESID,bool F32>
__device__ __forceinline__ void conv_body(const void* __restrict__ feats,
                                          const int4* __restrict__ coords,
                                          const int2* __restrict__ hash,
                                          const void* __restrict__ Wk,
                                          char* __restrict__ ob){
  constexpr size_t ESZ=F32?4:2;
  uint16_t* buf0=(uint16_t*)(ob+(size_t)PBZ_CELLS*64*ESZ);
  uint16_t* buf1=buf0+(size_t)N_*64;
  int wave=blockIdx.x*4+(threadIdx.x>>6);
  int lane=threadIdx.x&63;
  if(wave>=N_) return;
  int4 c=coords[wave];
  int z=c.y,y=c.z,x=c.w;
  float acc=0.f;
  #pragma unroll
  for(int k=0;k<9;k++){
    const int d0=k/3-1, dxo=k%3-1;
    int nz=AXIS31? z+d0:z;
    int ny=AXIS31? y:y+d0;
    int nx=x+dxo;
    int nidx=-1;
    if(nz>=0&&nz<D_&&ny>=0&&ny<H_&&nx>=0&&nx<W_)
      nidx=hlookup(hash,(nz*H_+ny)*W_+nx);
    nidx=__builtin_amdgcn_readfirstlane(nidx);
    if(nidx<0) continue;
    size_t fb=(size_t)nidx*CIN;
    size_t wb=(size_t)k*CIN*64+lane;
    #pragma unroll
    for(int ci=0;ci<CIN;ci+=2){
      float f0=(SRC==0)? ldv<F32>(feats,fb+ci)   : bf2f(buf0[fb+ci]);
      float f1=(SRC==0)? ldv<F32>(feats,fb+ci+1) : bf2f(buf0[fb+ci+1]);
      acc += f0*ldv<F32>(Wk,wb+(size_t)ci*64);
      acc += f1*ldv<F32>(Wk,wb+(size_t)(ci+1)*64);
    }
  }
  float v=acc>0.f? acc:0.01f*acc;
  if(RESID) v+=bf2f(buf1[(size_t)wave*64+lane]);
  size_t oi=(size_t)wave*64+lane;
  if(DST==0)      buf0[oi]=f2bf(v);
  else if(DST==1) buf1[oi]=f2bf(v);
  else            stv<F32>(ob+(size_t)NCELL*64*ESZ,oi,v);
}
template<int CIN,bool AXIS31,int SRC,int DST,bool RESID>
__global__ __launch_bounds__(256)
void k_conv(const void* feats,const int4* coords,const int2* hash,const void* Wk,
            char* ob,const int* flag){
  if(flag[0]) conv_body<CIN,AXIS31,SRC,DST,RESID,true >(feats,coords,hash,Wk,ob);
  else        conv_body<CIN,AXIS31,SRC,DST,RESID,false>(feats,coords,hash,Wk,ob);
}
template<bool F32>
__device__ __forceinline__ float pool_cell_t(int cell,const void* __restrict__ rA,
    const int2* __restrict__ hash,const void* __restrict__ Wp,int lane){
  int ox=cell&(WO_-1);
  int t=cell>>4;
  int oy=t%HO_, oz=t/HO_;
  float acc=0.f;
  int k=0;
  for(int kd=0;kd<3;kd++)for(int kh=0;kh<3;kh++)for(int kw=0;kw<3;kw++,k++){
    int z=2*oz+kd-1, y=2*oy+kh-1, x=2*ox+kw-1;
    if(z<0||z>=D_||y<0||y>=H_||x<0||x>=W_) continue;
    int nidx=hlookup(hash,(z*H_+y)*W_+x);
    nidx=__builtin_amdgcn_readfirstlane(nidx);
    if(nidx<0) continue;
    size_t fb=(size_t)nidx*64;
    size_t wb=(size_t)k*4096+lane;
    #pragma unroll
    for(int ci=0;ci<64;ci+=2){
      acc+=ldv<F32>(rA,fb+ci)  *ldv<F32>(Wp,wb+(size_t)ci*64);
      acc+=ldv<F32>(rA,fb+ci+1)*ldv<F32>(Wp,wb+(size_t)(ci+1)*64);
    }
  }
  return acc;
}
template<bool F32>
__device__ __forceinline__ void pool_fb_body(const void* __restrict__ Wp,
                                             char* __restrict__ ob,
                                             int* __restrict__ cnt){
  constexpr size_t ESZ=F32?4:2;
  const int2* hash=(const int2*)ob;
  const void* rA=ob+(size_t)NCELL*64*ESZ;
  int w=blockIdx.x*4+(threadIdx.x>>6);
  int lane=threadIdx.x&63;
  for(int cell=PBZ_CELLS+w; cell<NCELL; cell+=POOL_WAVES)
    stv<F32>(ob,(size_t)cell*64+lane, pool_cell_t<F32>(cell,rA,hash,Wp,lane));
  float accb[PB_PER_WAVE];
  #pragma unroll
  for(int j=0;j<PB_PER_WAVE;j++)
    accb[j]=pool_cell_t<F32>(w*PB_PER_WAVE+j,rA,hash,Wp,lane);
  __syncthreads();
  if(threadIdx.x==0){
    __threadfence();
    atomicAdd(cnt,1);
    while(atomicAdd(cnt,0)<POOL_BLOCKS) __builtin_amdgcn_s_sleep(8);
  }
  __syncthreads();
  #pragma unroll
  for(int j=0;j<PB_PER_WAVE;j++)
    stv<F32>(ob,(size_t)(w*PB_PER_WAVE+j)*64+lane,accb[j]);
}
__global__ __launch_bounds__(256,2)
void k_pool_fb(const void* Wp,char* ob,int* cnt,const int* flag){
  if(flag[0]) pool_fb_body<true >(Wp,ob,cnt);
  else        pool_fb_body<false>(Wp,ob,cnt);
}

extern "C" void kernel_launch(void* const* d_in,const int* in_sizes,int n_in,
                              void* d_out,int out_size,void* d_ws,size_t ws_size,
                              hipStream_t stream){
  const uint16_t* feats_u16=(const uint16_t*)d_in[0];
  const void* feats=d_in[0];
  const int4* coords=(const int4*)d_in[1];
  const void* W1  =d_in[2];
  const void* W1_2=d_in[3];
  const void* W2  =d_in[4];
  const void* W3  =d_in[5];
  const void* Wp  =d_in[6];
  char* ob=(char*)d_out;
  int* flag=(int*)d_ws;                       // [0]=dtype, [1]=barrier, [32..76]=counters

  // ws layout (main path):
  //   [0,512)    flags + 45 list counters (at byte 128)
  //   +512       dense table           22.1 MB
  //   +          listA (9*CAPC int2)    1.2 MB
  //   +          listB (9*CAPC int2)    1.2 MB
  //   +          listP (27*CAPP int2)   7.1 MB   => ~31.6 MB total
  const size_t OFF_TABLE=512;
  const size_t OFF_LISTA=OFF_TABLE+(size_t)NVOX*4;
  const size_t OFF_LISTB=OFF_LISTA+(size_t)9*CAPC*8;
  const size_t OFF_LISTP=OFF_LISTB+(size_t)9*CAPC*8;
  const size_t WS_NEED  =OFF_LISTP+(size_t)27*CAPP*8;
  const bool ws_ok = ws_size >= WS_NEED;

  int* cnt =flag+32;
  int* cntA=cnt, *cntB=cnt+9, *cntP=cnt+18;
  int*  table=(int*)((char*)d_ws+OFF_TABLE);
  int2* listA=(int2*)((char*)d_ws+OFF_LISTA);
  int2* listB=(int2*)((char*)d_ws+OFF_LISTB);
  int2* listP=(int2*)((char*)d_ws+OFF_LISTP);

  // f32-mode buffers carved from d_out's pooled region (dead until pool):
  float* bufA=(float*)ob;                          // 51.2 MB
  float* bufB=(float*)(ob+(size_t)N_*64*4);        // 51.2 MB (ends at 102.4 < 176.9)
  float* rAf =(float*)(ob+(size_t)NCELL*64*4);     // final rA region (f32 mode)

  k_sniff<<<1,256,0,stream>>>(feats_u16,flag);

  if(ws_ok){
    k_table_init <<<NVOX/4/256,256,0,stream>>>(table);
    k_table_build<<<(N_+255)/256,256,0,stream>>>(coords,table);
    k_build_conv <<<(N_+255)/256,256,0,stream>>>(coords,table,listA,listB,cntA,cntB,flag);
    k_build_pool <<<(N_+255)/256,256,0,stream>>>(coords,listP,cntP,flag);

    const float* W1f  =(const float*)W1;
    const float* W12f =(const float*)W1_2;
    const float* W2f  =(const float*)W2;
    const float* W3f  =(const float*)W3;
    const float* Wpf  =(const float*)Wp;
    const float* featsf=(const float*)feats;

    // L1: sc1 = leaky(subm(feats, W1, OFF_31)) -> bufA
    k_center<32><<<N_/16,256,0,stream>>>(featsf,W1f,bufA,flag);
    k_off<32><<<dim3(64,9),256,0,stream>>>(featsf,W1f,listA,cntA,bufA,flag);
    k_act<<<2048,256,0,stream>>>(bufA,flag);
    // L2: sc = leaky(subm(sc1, W1_2, OFF_13)) -> bufB
    k_center<64><<<N_/16,256,0,stream>>>(bufA,W12f,bufB,flag);
    k_off<64><<<dim3(64,9),256,0,stream>>>(bufA,W12f,listB,cntB,bufB,flag);
    k_act<<<2048,256,0,stream>>>(bufB,flag);
    // L3: rA1 = leaky(subm(feats, W2, OFF_13)) -> bufA (bufA dead after L2)
    k_center<32><<<N_/16,256,0,stream>>>(featsf,W2f,bufA,flag);
    k_off<32><<<dim3(64,9),256,0,stream>>>(featsf,W2f,listB,cntB,bufA,flag);
    k_act<<<2048,256,0,stream>>>(bufA,flag);
    // L4: rA = leaky(subm(rA1, W3, OFF_31)) + sc -> rAf
    k_center<64><<<N_/16,256,0,stream>>>(bufA,W3f,rAf,flag);
    k_off<64><<<dim3(64,9),256,0,stream>>>(bufA,W3f,listA,cntA,rAf,flag);
    k_act_resid<<<2048,256,0,stream>>>(rAf,bufB,flag);
    // pool: zero output (bufs dead), scatter-add streams
    k_zero<<<4096,256,0,stream>>>((float*)ob,flag);
    k_pools<<<dim3(96,27),256,0,stream>>>(rAf,Wpf,listP,cntP,(float*)ob,flag);

    // bf16-mode path (no-ops when flag[0]==1)
    k_convb<32,true ,0,0,false><<<N_/4,256,0,stream>>>(feats,coords,table,W1  ,ob,flag);
    k_convb<64,false,1,1,false><<<N_/4,256,0,stream>>>(feats,coords,table,W1_2,ob,flag);
    k_convb<32,false,0,0,false><<<N_/4,256,0,stream>>>(feats,coords,table,W2  ,ob,flag);
    k_convb<64,true ,1,2,true ><<<N_/4,256,0,stream>>>(feats,coords,table,W3  ,ob,flag);
    k_poolb<<<NCELL/8,256,0,stream>>>(table,Wp,ob,flag);
  }else{
    int2* hash=(int2*)ob;
    k_hash_init<<<(HSZ+255)/256,256,0,stream>>>(hash);
    k_hash_build<<<(N_+255)/256,256,0,stream>>>(coords,hash);
    k_conv<32,true ,0,0,false><<<N_/4,256,0,stream>>>(feats,coords,hash,W1  ,ob,flag);
    k_conv<64,false,1,1,false><<<N_/4,256,0,stream>>>(feats,coords,hash,W1_2,ob,flag);
    k_conv<32,false,0,0,false><<<N_/4,256,0,stream>>>(feats,coords,hash,W2  ,ob,flag);
    k_conv<64,true ,1,2,true ><<<N_/4,256,0,stream>>>(feats,coords,hash,W3  ,ob,flag);
    k_pool_fb<<<POOL_BLOCKS,256,0,stream>>>(Wp,ob,flag+1,flag);
  }
}

// Round 4
// 965.542 us; speedup vs baseline: 2.9408x; 2.3770x over previous
//
#include <hip/hip_runtime.h>
#include <stdint.h>

#define D_  480
#define H_  360
#define W_  32
#define N_  200000
#define DO_ 240
#define HO_ 180
#define WO_ 16
#define NCELL (DO_*HO_*WO_)     // 691,200
#define NVOX  (D_*H_*W_)        // 5,529,600
#define HBITS 19
#define HSZ   (1<<HBITS)
#define HMASK (HSZ-1)
#define CAPC 16384              // per off-center conv tap (expect ~7.2k)
#define CAPP 32768              // per pool tap (expect ~25k)
#define CSTRIDE 32              // counter padding: 32 ints = 128 B per counter

// fallback persistent pool constants
#define PBZ_CELLS 32768
#define POOL_BLOCKS 512
#define POOL_WAVES (POOL_BLOCKS*4)
#define PB_PER_WAVE (PBZ_CELLS/POOL_WAVES)   // 16

__device__ __forceinline__ float bf2f(uint16_t u){
  uint32_t x=((uint32_t)u)<<16; return __builtin_bit_cast(float,x);
}
__device__ __forceinline__ uint16_t f2bf(float f){
  uint32_t x=__builtin_bit_cast(uint32_t,f);
  uint32_t r=x+0x7fffu+((x>>16)&1u);          // RNE
  return (uint16_t)(r>>16);
}
template<bool F32> __device__ __forceinline__ float ldv(const void* p,size_t i){
  if constexpr(F32) return ((const float*)p)[i];
  else return bf2f(((const uint16_t*)p)[i]);
}
template<bool F32> __device__ __forceinline__ void stv(void* p,size_t i,float v){
  if constexpr(F32) ((float*)p)[i]=v;
  else ((uint16_t*)p)[i]=f2bf(v);
}
// broadcast-load 8 consecutive values -> f32[8] (bf16 path)
template<bool F32> __device__ __forceinline__ void ld8(const void* p,size_t base,float* v){
  if constexpr(F32){
    const float4* q=(const float4*)((const float*)p+base);
    float4 a=q[0], b=q[1];
    v[0]=a.x;v[1]=a.y;v[2]=a.z;v[3]=a.w;
    v[4]=b.x;v[5]=b.y;v[6]=b.z;v[7]=b.w;
  }else{
    const uint4* q=(const uint4*)((const uint16_t*)p+base);
    uint4 a=q[0];
    v[0]=bf2f((uint16_t)(a.x&0xffffu)); v[1]=bf2f((uint16_t)(a.x>>16));
    v[2]=bf2f((uint16_t)(a.y&0xffffu)); v[3]=bf2f((uint16_t)(a.y>>16));
    v[4]=bf2f((uint16_t)(a.z&0xffffu)); v[5]=bf2f((uint16_t)(a.z>>16));
    v[6]=bf2f((uint16_t)(a.w&0xffffu)); v[7]=bf2f((uint16_t)(a.w>>16));
  }
}
// register-file broadcast (ci is compile-time in unrolled loops)
__device__ __forceinline__ float rlane(float v,int l){
  return __builtin_bit_cast(float,
      __builtin_amdgcn_readlane(__builtin_bit_cast(int,v),l));
}
__device__ __forceinline__ float lk(float v){ return v>0.f? v:0.01f*v; }

__device__ __forceinline__ uint32_t hash0(int lin){
  return ((uint32_t)((uint32_t)lin*2654435761u)>>12)&HMASK;
}
__device__ __forceinline__ int hlookup(const int2* __restrict__ h,int lin){
  uint32_t s=hash0(lin);
  for(;;){ int2 kv=h[s]; if(kv.x==lin) return kv.y; if(kv.x<0) return -1; s=(s+1)&HMASK; }
}

// dtype sniff: flag[0]=1 iff inputs are f32. Zeroes flag[1] + 45 PADDED counters
// (counters live at flag[128 + t*CSTRIDE], one per 128-B cache line).
__global__ void k_sniff(const uint16_t* __restrict__ feats,int* __restrict__ flag){
  __shared__ int s;
  if(threadIdx.x==0) s=0;
  __syncthreads();
  int bad=0;
  for(int i=threadIdx.x;i<512;i+=256){
    int e=(feats[i]>>7)&0xff;
    bad += (e>=0x90)?1:0;
  }
  atomicAdd(&s,bad);
  if(threadIdx.x<45) flag[128+threadIdx.x*CSTRIDE]=0;
  __syncthreads();
  if(threadIdx.x==0){ flag[0]=(s>=8)?1:0; flag[1]=0; }
}

// ---------------- dense direct-index voxel table (lives in ws) ----------------
__global__ void k_table_init(int* __restrict__ t){
  int i=blockIdx.x*256+threadIdx.x;
  if(i<NVOX/4) ((int4*)t)[i]=make_int4(-1,-1,-1,-1);
}
__global__ void k_table_build(const int4* __restrict__ coords,int* __restrict__ t){
  int i=blockIdx.x*256+threadIdx.x;
  if(i>=N_) return;
  int4 c=coords[i];                      // (b,z,y,x), b==0
  t[(c.y*H_+c.z)*W_+c.w]=i;
}

// ---------------- legacy hash (fallback path only) ----------------
__global__ void k_hash_init(int2* __restrict__ h){
  int i=blockIdx.x*256+threadIdx.x;
  if(i<HSZ) h[i]=make_int2(-1,-1);
}
__global__ void k_hash_build(const int4* __restrict__ coords,int2* __restrict__ h){
  int i=blockIdx.x*256+threadIdx.x;
  if(i>=N_) return;
  int4 c=coords[i];
  int lin=(c.y*H_+c.z)*W_+c.w;
  uint32_t s=hash0(lin);
  for(;;){
    int old=atomicCAS(&h[s].x,-1,lin);
    if(old==-1){ h[s].y=i; break; }
    s=(s+1)&HMASK;
  }
}

// =================================================================
// MAIN F32 PATH: k-grouped pair lists + register-resident weights
// =================================================================

// wave-aggregated list append (one atomic per wave per tap; counter padded)
__device__ __forceinline__ void wappend(int2* __restrict__ lst,int* __restrict__ cnt,
                                        int cap,int a,int b,bool want,int lane){
  unsigned long long m=__ballot(want);
  if(m==0ull) return;
  int first=__builtin_ctzll(m);
  int base=0;
  if(lane==first) base=atomicAdd(cnt,__popcll(m));
  base=__shfl(base,first);
  if(want){
    int pref=__popcll(m&((1ull<<lane)-1ull));
    int pos=base+pref;
    if(pos<cap) lst[pos]=make_int2(a,b);
  }
}

// conv pair lists for both offset patterns; tap order staggered per block so
// concurrent atomics spread across all (padded) counter lines.
__global__ __launch_bounds__(256)
void k_build_conv(const int4* __restrict__ coords,const int* __restrict__ table,
                  int2* __restrict__ listA,int2* __restrict__ listB,
                  int* __restrict__ cntA,int* __restrict__ cntB,
                  const int* __restrict__ flag){
  if(!flag[0]) return;
  int i=blockIdx.x*256+threadIdx.x;
  bool valid=i<N_;
  int4 c = valid? coords[i] : make_int4(0,0,0,0);
  int z=c.y,y=c.z,x=c.w;
  int lane=threadIdx.x&63;
  #pragma unroll
  for(int j=0;j<9;j++){
    int k=(blockIdx.x+j)%9;
    if(k==4) continue;
    int d0=k/3-1, dx=k%3-1;
    { // pattern A (OFF_31): (dz,0,dx)
      int nz=z+d0, nx=x+dx;
      int src=-1;
      if(valid && nz>=0&&nz<D_&&nx>=0&&nx<W_) src=table[(nz*H_+y)*W_+nx];
      wappend(listA+(size_t)k*CAPC,&cntA[k*CSTRIDE],CAPC,i,src,src>=0,lane);
    }
    { // pattern B (OFF_13): (0,dy,dx)
      int ny=y+d0, nx=x+dx;
      int src=-1;
      if(valid && ny>=0&&ny<H_&&nx>=0&&nx<W_) src=table[(z*H_+ny)*W_+nx];
      wappend(listB+(size_t)k*CAPC,&cntB[k*CSTRIDE],CAPC,i,src,src>=0,lane);
    }
  }
}

// pool pair lists; staggered tap order
__global__ __launch_bounds__(256)
void k_build_pool(const int4* __restrict__ coords,int2* __restrict__ listP,
                  int* __restrict__ cntP,const int* __restrict__ flag){
  if(!flag[0]) return;
  int i=blockIdx.x*256+threadIdx.x;
  bool valid=i<N_;
  int4 c = valid? coords[i] : make_int4(0,0,0,0);
  int z=c.y,y=c.z,x=c.w;
  int lane=threadIdx.x&63;
  #pragma unroll
  for(int j=0;j<27;j++){
    int k=(blockIdx.x+j)%27;
    int kd=k/9, kh=(k/3)%3, kw=k%3;
    int tz=z+1-kd, ty=y+1-kh, tx=x+1-kw;
    bool ok = valid && !(tz&1)&&!(ty&1)&&!(tx&1);
    int oz=tz>>1, oy=ty>>1, ox=tx>>1;
    ok = ok && oz>=0&&oz<DO_&&oy>=0&&oy<HO_&&ox>=0&&ox<WO_;
    int cell = ok? ((oz*HO_+oy)*WO_+ox) : -1;
    wappend(listP+(size_t)k*CAPP,&cntP[k*CSTRIDE],CAPP,cell,i,ok,lane);
  }
}

// center tap (k=4): dst row p = act(src row p) @ W[4]; bijection -> plain store.
// ACT: apply leaky to the source row on read (fused previous-layer activation).
template<int CIN,bool ACT>
__global__ __launch_bounds__(256)
void k_center(const float* __restrict__ src,const float* __restrict__ Wl,
              float* __restrict__ dst,const int* __restrict__ flag){
  if(!flag[0]) return;
  int wave=blockIdx.x*4+(threadIdx.x>>6);
  int lane=threadIdx.x&63;
  int p0=wave*4;                        // N_ % 16 == 0 -> exact
  if(p0>=N_) return;
  float w[CIN];
  #pragma unroll
  for(int ci=0;ci<CIN;ci++) w[ci]=Wl[(size_t)4*CIN*64+(size_t)ci*64+lane];
  int li=(CIN==64)? lane : (lane&31);
  float r0=src[(size_t)(p0+0)*CIN+li];
  float r1=src[(size_t)(p0+1)*CIN+li];
  float r2=src[(size_t)(p0+2)*CIN+li];
  float r3=src[(size_t)(p0+3)*CIN+li];
  if(ACT){ r0=lk(r0); r1=lk(r1); r2=lk(r2); r3=lk(r3); }
  float a0=0.f,a1=0.f,a2=0.f,a3=0.f;
  #pragma unroll
  for(int ci=0;ci<CIN;ci++){
    float wc=w[ci];
    a0+=rlane(r0,ci)*wc; a1+=rlane(r1,ci)*wc;
    a2+=rlane(r2,ci)*wc; a3+=rlane(r3,ci)*wc;
  }
  dst[(size_t)(p0+0)*64+lane]=a0;
  dst[(size_t)(p0+1)*64+lane]=a1;
  dst[(size_t)(p0+2)*64+lane]=a2;
  dst[(size_t)(p0+3)*64+lane]=a3;
}

// off-center conv taps: stream (dst,src) pairs of tap g, atomicAdd into dst rows
template<int CIN,bool ACT>
__global__ __launch_bounds__(256)
void k_off(const float* __restrict__ src,const float* __restrict__ Wl,
           const int2* __restrict__ lists,const int* __restrict__ cnt,
           float* __restrict__ dst,const int* __restrict__ flag){
  if(!flag[0]) return;
  int g=blockIdx.y;
  if(g==4) return;
  int n=min(cnt[g*CSTRIDE],CAPC);
  const int2* lst=lists+(size_t)g*CAPC;
  int wave=blockIdx.x*4+(threadIdx.x>>6);
  int lane=threadIdx.x&63;
  float w[CIN];
  #pragma unroll
  for(int ci=0;ci<CIN;ci++) w[ci]=Wl[(size_t)g*CIN*64+(size_t)ci*64+lane];
  int nw=gridDim.x*4;
  int li=(CIN==64)? lane : (lane&31);
  for(int p=wave;p<n;p+=nw){
    int2 pr=lst[p];                     // (dst, src)
    float r=src[(size_t)pr.y*CIN+li];
    if(ACT) r=lk(r);
    float a=0.f;
    #pragma unroll
    for(int ci=0;ci<CIN;ci++) a+=rlane(r,ci)*w[ci];
    atomicAdd(&dst[(size_t)pr.x*64+lane],a);
  }
}

// pool stream: tap g weights resident; 4 (cell,voxel) pairs in flight
__global__ __launch_bounds__(256)
void k_pools(const float* __restrict__ rAp,const float* __restrict__ Wp,
             const int2* __restrict__ listP,const int* __restrict__ cntP,
             float* __restrict__ out,const int* __restrict__ flag){
  if(!flag[0]) return;
  int g=blockIdx.y;
  int n=min(cntP[g*CSTRIDE],CAPP);
  const int2* lst=listP+(size_t)g*CAPP;
  int wave=blockIdx.x*4+(threadIdx.x>>6);
  int lane=threadIdx.x&63;
  float w[64];
  #pragma unroll
  for(int ci=0;ci<64;ci++) w[ci]=Wp[(size_t)g*4096+(size_t)ci*64+lane];
  int nw=gridDim.x*4;
  for(int p0=wave*4;p0<n;p0+=nw*4){
    int pB=p0+1,pC=p0+2,pD=p0+3;
    bool vB=pB<n, vC=pC<n, vD=pD<n;
    int2 qA=lst[p0];
    int2 qB=vB?lst[pB]:qA;
    int2 qC=vC?lst[pC]:qA;
    int2 qD=vD?lst[pD]:qA;
    float rA_=rAp[(size_t)qA.y*64+lane];
    float rB_=rAp[(size_t)qB.y*64+lane];
    float rC_=rAp[(size_t)qC.y*64+lane];
    float rD_=rAp[(size_t)qD.y*64+lane];
    float aA=0.f,aB=0.f,aC=0.f,aD=0.f;
    #pragma unroll
    for(int ci=0;ci<64;ci++){
      float wc=w[ci];
      aA+=rlane(rA_,ci)*wc;
      aB+=rlane(rB_,ci)*wc;
      aC+=rlane(rC_,ci)*wc;
      aD+=rlane(rD_,ci)*wc;
    }
    atomicAdd(&out[(size_t)qA.x*64+lane],aA);
    if(vB) atomicAdd(&out[(size_t)qB.x*64+lane],aB);
    if(vC) atomicAdd(&out[(size_t)qC.x*64+lane],aC);
    if(vD) atomicAdd(&out[(size_t)qD.x*64+lane],aD);
  }
}

// rA = leaky(raw L4) + leaky(raw sc)   (both activations fused here)
__global__ __launch_bounds__(256)
void k_act_resid(float* __restrict__ r,const float* __restrict__ sc,
                 const int* __restrict__ flag){
  if(!flag[0]) return;
  size_t n=(size_t)N_*64;
  size_t stride=(size_t)gridDim.x*1024;
  for(size_t i=((size_t)blockIdx.x*256+threadIdx.x)*4;i<n;i+=stride){
    float4 v=*(float4*)(r+i);
    float4 s=*(const float4*)(sc+i);
    v.x=lk(v.x)+lk(s.x); v.y=lk(v.y)+lk(s.y);
    v.z=lk(v.z)+lk(s.z); v.w=lk(v.w)+lk(s.w);
    *(float4*)(r+i)=v;
  }
}
__global__ __launch_bounds__(256)
void k_zero(float* __restrict__ out,const int* __restrict__ flag){
  if(!flag[0]) return;
  size_t n=(size_t)NCELL*64;
  size_t stride=(size_t)gridDim.x*1024;
  float4 z=make_float4(0.f,0.f,0.f,0.f);
  for(size_t i=((size_t)blockIdx.x*256+threadIdx.x)*4;i<n;i+=stride)
    *(float4*)(out+i)=z;
}

// =================================================================
// BF16 MAIN PATH (flag==0): verified R1 gather kernels, bufs in ob scratch
// =================================================================
template<int CIN,bool AXIS31,int SRC,int DST,bool RESID>
__global__ __launch_bounds__(256)
void k_convb(const void* __restrict__ feats,const int4* __restrict__ coords,
             const int* __restrict__ table,const void* __restrict__ Wk,
             char* __restrict__ ob,const int* __restrict__ flag){
  if(flag[0]) return;
  uint16_t* buf0=(uint16_t*)ob;
  uint16_t* buf1=buf0+(size_t)N_*64;
  int wave=blockIdx.x*4+(threadIdx.x>>6);
  int lane=threadIdx.x&63;
  if(wave>=N_) return;
  int4 c=coords[wave];
  int z=c.y,y=c.z,x=c.w;
  int nidx=-1;
  if(lane<9){
    int d0=lane/3-1, dxo=lane%3-1;
    int nz=AXIS31? z+d0:z;
    int ny=AXIS31? y:y+d0;
    int nx=x+dxo;
    if(nz>=0&&nz<D_&&ny>=0&&ny<H_&&nx>=0&&nx<W_)
      nidx=table[(nz*H_+ny)*W_+nx];
  }
  unsigned long long m=__ballot(nidx>=0);
  float acc=0.f;
  while(m){
    int k=__builtin_ctzll(m); m&=m-1;
    int idx=__shfl(nidx,k);
    size_t fb=(size_t)idx*CIN;
    size_t wb=(size_t)k*CIN*64+lane;
    #pragma unroll
    for(int g=0;g<CIN/8;g++){
      float f[8];
      if(SRC==0) ld8<false>(feats,fb+(size_t)8*g,f);
      else       ld8<false>(buf0 ,fb+(size_t)8*g,f);
      #pragma unroll
      for(int j=0;j<8;j++)
        acc+=f[j]*ldv<false>(Wk,wb+(size_t)(8*g+j)*64);
    }
  }
  float v=acc>0.f? acc:0.01f*acc;
  if(RESID) v+=bf2f(buf1[(size_t)wave*64+lane]);
  size_t oi=(size_t)wave*64+lane;
  if(DST==0)      buf0[oi]=f2bf(v);
  else if(DST==1) buf1[oi]=f2bf(v);
  else            stv<false>(ob+(size_t)NCELL*64*2,oi,v);
}

__global__ __launch_bounds__(256)
void k_poolb(const int* __restrict__ table,const void* __restrict__ Wp,
             char* __restrict__ ob,const int* __restrict__ flag){
  if(flag[0]) return;
  const char* rAp=ob+(size_t)NCELL*64*2;
  int wave=blockIdx.x*4+(threadIdx.x>>6);
  int lane=threadIdx.x&63;
  int cell0=wave*2;
  if(cell0>=NCELL) return;
  int half=lane>>5, l=lane&31;
  int cell=cell0+half;
  int ox=cell&(WO_-1);
  int t=cell>>4;
  int oy=t%HO_, oz=t/HO_;
  int nidx=-1;
  if(l<27){
    int kd=l/9, kh=(l/3)%3, kw=l%3;
    int z=2*oz+kd-1, y=2*oy+kh-1, x=2*ox+kw-1;
    if(z>=0&&z<D_&&y>=0&&y<H_&&x>=0&&x<W_)
      nidx=table[(z*H_+y)*W_+x];
  }
  unsigned long long m=__ballot(nidx>=0);
  unsigned int ma=(unsigned int)(m&0x07FFFFFFull);
  unsigned int mb=(unsigned int)((m>>32)&0x07FFFFFFull);
  float acc0=0.f, acc1=0.f;
  while(ma|mb){
    int ka=-1,kb=-1,ia=0,ib=0;
    if(ma){ ka=__builtin_ctz(ma); ma&=ma-1; ia=__shfl(nidx,ka); }
    if(mb){ kb=__builtin_ctz(mb); mb&=mb-1; ib=__shfl(nidx,32+kb); }
    if(ka>=0){
      size_t fb=(size_t)ia*64, wb=(size_t)ka*4096+lane;
      #pragma unroll
      for(int g=0;g<8;g++){
        float f[8]; ld8<false>(rAp,fb+(size_t)8*g,f);
        #pragma unroll
        for(int j=0;j<8;j++) acc0+=f[j]*ldv<false>(Wp,wb+(size_t)(8*g+j)*64);
      }
    }
    if(kb>=0){
      size_t fb=(size_t)ib*64, wb=(size_t)kb*4096+lane;
      #pragma unroll
      for(int g=0;g<8;g++){
        float f[8]; ld8<false>(rAp,fb+(size_t)8*g,f);
        #pragma unroll
        for(int j=0;j<8;j++) acc1+=f[j]*ldv<false>(Wp,wb+(size_t)(8*g+j)*64);
      }
    }
  }
  stv<false>(ob,(size_t)cell0*64+lane,acc0);
  stv<false>(ob,((size_t)cell0+1)*64+lane,acc1);
}

// =================================================================
// FALLBACK PATH (ws too small): legacy hash-based kernels, unchanged
// =================================================================
template<int CIN,bool AXIS31,int SRC,int DST,bool RESID,bool F32>
__device__ __forceinline__ void conv_body(const void* __restrict__ feats,
                                          const int4* __restrict__ coords,
                                          const int2* __restrict__ hash,
                                          const void* __restrict__ Wk,
                                          char* __restrict__ ob){
  constexpr size_t ESZ=F32?4:2;
  uint16_t* buf0=(uint16_t*)(ob+(size_t)PBZ_CELLS*64*ESZ);
  uint16_t* buf1=buf0+(size_t)N_*64;
  int wave=blockIdx.x*4+(threadIdx.x>>6);
  int lane=threadIdx.x&63;
  if(wave>=N_) return;
  int4 c=coords[wave];
  int z=c.y,y=c.z,x=c.w;
  float acc=0.f;
  #pragma unroll
  for(int k=0;k<9;k++){
    const int d0=k/3-1, dxo=k%3-1;
    int nz=AXIS31? z+d0:z;
    int ny=AXIS31? y:y+d0;
    int nx=x+dxo;
    int nidx=-1;
    if(nz>=0&&nz<D_&&ny>=0&&ny<H_&&nx>=0&&nx<W_)
      nidx=hlookup(hash,(nz*H_+ny)*W_+nx);
    nidx=__builtin_amdgcn_readfirstlane(nidx);
    if(nidx<0) continue;
    size_t fb=(size_t)nidx*CIN;
    size_t wb=(size_t)k*CIN*64+lane;
    #pragma unroll
    for(int ci=0;ci<CIN;ci+=2){
      float f0=(SRC==0)? ldv<F32>(feats,fb+ci)   : bf2f(buf0[fb+ci]);
      float f1=(SRC==0)? ldv<F32>(feats,fb+ci+1) : bf2f(buf0[fb+ci+1]);
      acc += f0*ldv<F32>(Wk,wb+(size_t)ci*64);
      acc += f1*ldv<F32>(Wk,wb+(size_t)(ci+1)*64);
    }
  }
  float v=acc>0.f? acc:0.01f*acc;
  if(RESID) v+=bf2f(buf1[(size_t)wave*64+lane]);
  size_t oi=(size_t)wave*64+lane;
  if(DST==0)      buf0[oi]=f2bf(v);
  else if(DST==1) buf1[oi]=f2bf(v);
  else            stv<F32>(ob+(size_t)NCELL*64*ESZ,oi,v);
}
template<int CIN,bool AXIS31,int SRC,int DST,bool RESID>
__global__ __launch_bounds__(256)
void k_conv(const void* feats,const int4* coords,const int2* hash,const void* Wk,
            char* ob,const int* flag){
  if(flag[0]) conv_body<CIN,AXIS31,SRC,DST,RESID,true >(feats,coords,hash,Wk,ob);
  else        conv_body<CIN,AXIS31,SRC,DST,RESID,false>(feats,coords,hash,Wk,ob);
}
template<bool F32>
__device__ __forceinline__ float pool_cell_t(int cell,const void* __restrict__ rA,
    const int2* __restrict__ hash,const void* __restrict__ Wp,int lane){
  int ox=cell&(WO_-1);
  int t=cell>>4;
  int oy=t%HO_, oz=t/HO_;
  float acc=0.f;
  int k=0;
  for(int kd=0;kd<3;kd++)for(int kh=0;kh<3;kh++)for(int kw=0;kw<3;kw++,k++){
    int z=2*oz+kd-1, y=2*oy+kh-1, x=2*ox+kw-1;
    if(z<0||z>=D_||y<0||y>=H_||x<0||x>=W_) continue;
    int nidx=hlookup(hash,(z*H_+y)*W_+x);
    nidx=__builtin_amdgcn_readfirstlane(nidx);
    if(nidx<0) continue;
    size_t fb=(size_t)nidx*64;
    size_t wb=(size_t)k*4096+lane;
    #pragma unroll
    for(int ci=0;ci<64;ci+=2){
      acc+=ldv<F32>(rA,fb+ci)  *ldv<F32>(Wp,wb+(size_t)ci*64);
      acc+=ldv<F32>(rA,fb+ci+1)*ldv<F32>(Wp,wb+(size_t)(ci+1)*64);
    }
  }
  return acc;
}
template<bool F32>
__device__ __forceinline__ void pool_fb_body(const void* __restrict__ Wp,
                                             char* __restrict__ ob,
                                             int* __restrict__ cnt){
  constexpr size_t ESZ=F32?4:2;
  const int2* hash=(const int2*)ob;
  const void* rA=ob+(size_t)NCELL*64*ESZ;
  int w=blockIdx.x*4+(threadIdx.x>>6);
  int lane=threadIdx.x&63;
  for(int cell=PBZ_CELLS+w; cell<NCELL; cell+=POOL_WAVES)
    stv<F32>(ob,(size_t)cell*64+lane, pool_cell_t<F32>(cell,rA,hash,Wp,lane));
  float accb[PB_PER_WAVE];
  #pragma unroll
  for(int j=0;j<PB_PER_WAVE;j++)
    accb[j]=pool_cell_t<F32>(w*PB_PER_WAVE+j,rA,hash,Wp,lane);
  __syncthreads();
  if(threadIdx.x==0){
    __threadfence();
    atomicAdd(cnt,1);
    while(atomicAdd(cnt,0)<POOL_BLOCKS) __builtin_amdgcn_s_sleep(8);
  }
  __syncthreads();
  #pragma unroll
  for(int j=0;j<PB_PER_WAVE;j++)
    stv<F32>(ob,(size_t)(w*PB_PER_WAVE+j)*64+lane,accb[j]);
}
__global__ __launch_bounds__(256,2)
void k_pool_fb(const void* Wp,char* ob,int* cnt,const int* flag){
  if(flag[0]) pool_fb_body<true >(Wp,ob,cnt);
  else        pool_fb_body<false>(Wp,ob,cnt);
}

extern "C" void kernel_launch(void* const* d_in,const int* in_sizes,int n_in,
                              void* d_out,int out_size,void* d_ws,size_t ws_size,
                              hipStream_t stream){
  const uint16_t* feats_u16=(const uint16_t*)d_in[0];
  const void* feats=d_in[0];
  const int4* coords=(const int4*)d_in[1];
  const void* W1  =d_in[2];
  const void* W1_2=d_in[3];
  const void* W2  =d_in[4];
  const void* W3  =d_in[5];
  const void* Wp  =d_in[6];
  char* ob=(char*)d_out;
  int* flag=(int*)d_ws;            // [0]=dtype, [1]=barrier, counters at +512B

  // ws layout (main path):
  //   [0,512)        flags
  //   [512, 6272)    45 padded counters (128 B each)
  //   8192           dense table         22.1 MB
  //   +              listA (9*CAPC int2)  1.2 MB
  //   +              listB (9*CAPC int2)  1.2 MB
  //   +              listP (27*CAPP int2) 7.1 MB  => ~31.6 MB total
  const size_t OFF_TABLE=8192;
  const size_t OFF_LISTA=OFF_TABLE+(size_t)NVOX*4;
  const size_t OFF_LISTB=OFF_LISTA+(size_t)9*CAPC*8;
  const size_t OFF_LISTP=OFF_LISTB+(size_t)9*CAPC*8;
  const size_t WS_NEED  =OFF_LISTP+(size_t)27*CAPP*8;
  const bool ws_ok = ws_size >= WS_NEED;

  int* cnt =flag+128;              // padded: counter t at cnt[t*CSTRIDE]
  int* cntA=cnt, *cntB=cnt+9*CSTRIDE, *cntP=cnt+18*CSTRIDE;
  int*  table=(int*)((char*)d_ws+OFF_TABLE);
  int2* listA=(int2*)((char*)d_ws+OFF_LISTA);
  int2* listB=(int2*)((char*)d_ws+OFF_LISTB);
  int2* listP=(int2*)((char*)d_ws+OFF_LISTP);

  // f32-mode buffers carved from d_out's pooled region (dead until pool):
  float* bufA=(float*)ob;                          // 51.2 MB
  float* bufB=(float*)(ob+(size_t)N_*64*4);        // 51.2 MB (ends at 102.4 < 176.9)
  float* rAf =(float*)(ob+(size_t)NCELL*64*4);     // final rA region (f32 mode)

  k_sniff<<<1,256,0,stream>>>(feats_u16,flag);

  if(ws_ok){
    k_table_init <<<NVOX/4/256,256,0,stream>>>(table);
    k_table_build<<<(N_+255)/256,256,0,stream>>>(coords,table);
    k_build_conv <<<(N_+255)/256,256,0,stream>>>(coords,table,listA,listB,cntA,cntB,flag);
    k_build_pool <<<(N_+255)/256,256,0,stream>>>(coords,listP,cntP,flag);

    const float* W1f  =(const float*)W1;
    const float* W12f =(const float*)W1_2;
    const float* W2f  =(const float*)W2;
    const float* W3f  =(const float*)W3;
    const float* Wpf  =(const float*)Wp;
    const float* featsf=(const float*)feats;

    // L1: raw1 = subm(feats, W1, OFF_31) -> bufA   (act fused into L2 reads)
    k_center<32,false><<<N_/16,256,0,stream>>>(featsf,W1f,bufA,flag);
    k_off<32,false><<<dim3(64,9),256,0,stream>>>(featsf,W1f,listA,cntA,bufA,flag);
    // L2: raw_sc = subm(lk(raw1), W1_2, OFF_13) -> bufB (act fused into resid)
    k_center<64,true ><<<N_/16,256,0,stream>>>(bufA,W12f,bufB,flag);
    k_off<64,true ><<<dim3(64,9),256,0,stream>>>(bufA,W12f,listB,cntB,bufB,flag);
    // L3: raw2 = subm(feats, W2, OFF_13) -> bufA   (act fused into L4 reads)
    k_center<32,false><<<N_/16,256,0,stream>>>(featsf,W2f,bufA,flag);
    k_off<32,false><<<dim3(64,9),256,0,stream>>>(featsf,W2f,listB,cntB,bufA,flag);
    // L4: raw3 = subm(lk(raw2), W3, OFF_31) -> rAf
    k_center<64,true ><<<N_/16,256,0,stream>>>(bufA,W3f,rAf,flag);
    k_off<64,true ><<<dim3(64,9),256,0,stream>>>(bufA,W3f,listA,cntA,rAf,flag);
    // rA = lk(raw3) + lk(raw_sc)
    k_act_resid<<<2048,256,0,stream>>>(rAf,bufB,flag);
    // pool: zero output (bufs dead), scatter-add streams
    k_zero<<<4096,256,0,stream>>>((float*)ob,flag);
    k_pools<<<dim3(96,27),256,0,stream>>>(rAf,Wpf,listP,cntP,(float*)ob,flag);

    // bf16-mode path (no-ops when flag[0]==1)
    k_convb<32,true ,0,0,false><<<N_/4,256,0,stream>>>(feats,coords,table,W1  ,ob,flag);
    k_convb<64,false,1,1,false><<<N_/4,256,0,stream>>>(feats,coords,table,W1_2,ob,flag);
    k_convb<32,false,0,0,false><<<N_/4,256,0,stream>>>(feats,coords,table,W2  ,ob,flag);
    k_convb<64,true ,1,2,true ><<<N_/4,256,0,stream>>>(feats,coords,table,W3  ,ob,flag);
    k_poolb<<<NCELL/8,256,0,stream>>>(table,Wp,ob,flag);
  }else{
    int2* hash=(int2*)ob;
    k_hash_init<<<(HSZ+255)/256,256,0,stream>>>(hash);
    k_hash_build<<<(N_+255)/256,256,0,stream>>>(coords,hash);
    k_conv<32,true ,0,0,false><<<N_/4,256,0,stream>>>(feats,coords,hash,W1  ,ob,flag);
    k_conv<64,false,1,1,false><<<N_/4,256,0,stream>>>(feats,coords,hash,W1_2,ob,flag);
    k_conv<32,false,0,0,false><<<N_/4,256,0,stream>>>(feats,coords,hash,W2  ,ob,flag);
    k_conv<64,true ,1,2,true ><<<N_/4,256,0,stream>>>(feats,coords,hash,W3  ,ob,flag);
    k_pool_fb<<<POOL_BLOCKS,256,0,stream>>>(Wp,ob,flag+1,flag);
  }
}

// Round 5
// 957.914 us; speedup vs baseline: 2.9642x; 1.0080x over previous
//
#include <hip/hip_runtime.h>
#include <stdint.h>

#define D_  480
#define H_  360
#define W_  32
#define N_  200000
#define DO_ 240
#define HO_ 180
#define WO_ 16
#define NCELL (DO_*HO_*WO_)     // 691,200
#define NVOX  (D_*H_*W_)        // 5,529,600
#define HBITS 19
#define HSZ   (1<<HBITS)
#define HMASK (HSZ-1)
#define CAPC 16384              // per off-center conv tap (expect ~7.2k)
#define CAPP 32768              // per pool tap (expect ~25k)
#define CSTRIDE 32              // counter padding: 32 ints = 128 B per counter

// fallback persistent pool constants
#define PBZ_CELLS 32768
#define POOL_BLOCKS 512
#define POOL_WAVES (POOL_BLOCKS*4)
#define PB_PER_WAVE (PBZ_CELLS/POOL_WAVES)   // 16

__device__ __forceinline__ float bf2f(uint16_t u){
  uint32_t x=((uint32_t)u)<<16; return __builtin_bit_cast(float,x);
}
__device__ __forceinline__ uint16_t f2bf(float f){
  uint32_t x=__builtin_bit_cast(uint32_t,f);
  uint32_t r=x+0x7fffu+((x>>16)&1u);          // RNE
  return (uint16_t)(r>>16);
}
template<bool F32> __device__ __forceinline__ float ldv(const void* p,size_t i){
  if constexpr(F32) return ((const float*)p)[i];
  else return bf2f(((const uint16_t*)p)[i]);
}
template<bool F32> __device__ __forceinline__ void stv(void* p,size_t i,float v){
  if constexpr(F32) ((float*)p)[i]=v;
  else ((uint16_t*)p)[i]=f2bf(v);
}
// broadcast-load 8 consecutive values -> f32[8] (bf16 path)
template<bool F32> __device__ __forceinline__ void ld8(const void* p,size_t base,float* v){
  if constexpr(F32){
    const float4* q=(const float4*)((const float*)p+base);
    float4 a=q[0], b=q[1];
    v[0]=a.x;v[1]=a.y;v[2]=a.z;v[3]=a.w;
    v[4]=b.x;v[5]=b.y;v[6]=b.z;v[7]=b.w;
  }else{
    const uint4* q=(const uint4*)((const uint16_t*)p+base);
    uint4 a=q[0];
    v[0]=bf2f((uint16_t)(a.x&0xffffu)); v[1]=bf2f((uint16_t)(a.x>>16));
    v[2]=bf2f((uint16_t)(a.y&0xffffu)); v[3]=bf2f((uint16_t)(a.y>>16));
    v[4]=bf2f((uint16_t)(a.z&0xffffu)); v[5]=bf2f((uint16_t)(a.z>>16));
    v[6]=bf2f((uint16_t)(a.w&0xffffu)); v[7]=bf2f((uint16_t)(a.w>>16));
  }
}
// register-file broadcast (ci is compile-time in unrolled loops)
__device__ __forceinline__ float rlane(float v,int l){
  return __builtin_bit_cast(float,
      __builtin_amdgcn_readlane(__builtin_bit_cast(int,v),l));
}
__device__ __forceinline__ float lk(float v){ return v>0.f? v:0.01f*v; }

__device__ __forceinline__ uint32_t hash0(int lin){
  return ((uint32_t)((uint32_t)lin*2654435761u)>>12)&HMASK;
}
__device__ __forceinline__ int hlookup(const int2* __restrict__ h,int lin){
  uint32_t s=hash0(lin);
  for(;;){ int2 kv=h[s]; if(kv.x==lin) return kv.y; if(kv.x<0) return -1; s=(s+1)&HMASK; }
}

// dtype sniff: flag[0]=1 iff inputs are f32. Zeroes flag[1] + 45 PADDED counters
// (counters live at flag[128 + t*CSTRIDE], one per 128-B cache line).
__global__ void k_sniff(const uint16_t* __restrict__ feats,int* __restrict__ flag){
  __shared__ int s;
  if(threadIdx.x==0) s=0;
  __syncthreads();
  int bad=0;
  for(int i=threadIdx.x;i<512;i+=256){
    int e=(feats[i]>>7)&0xff;
    bad += (e>=0x90)?1:0;
  }
  atomicAdd(&s,bad);
  if(threadIdx.x<45) flag[128+threadIdx.x*CSTRIDE]=0;
  __syncthreads();
  if(threadIdx.x==0){ flag[0]=(s>=8)?1:0; flag[1]=0; }
}

// ---------------- dense direct-index voxel table (lives in ws) ----------------
__global__ void k_table_init(int* __restrict__ t){
  int i=blockIdx.x*256+threadIdx.x;
  if(i<NVOX/4) ((int4*)t)[i]=make_int4(-1,-1,-1,-1);
}
__global__ void k_table_build(const int4* __restrict__ coords,int* __restrict__ t){
  int i=blockIdx.x*256+threadIdx.x;
  if(i>=N_) return;
  int4 c=coords[i];                      // (b,z,y,x), b==0
  t[(c.y*H_+c.z)*W_+c.w]=i;
}

// ---------------- legacy hash (fallback path only) ----------------
__global__ void k_hash_init(int2* __restrict__ h){
  int i=blockIdx.x*256+threadIdx.x;
  if(i<HSZ) h[i]=make_int2(-1,-1);
}
__global__ void k_hash_build(const int4* __restrict__ coords,int2* __restrict__ h){
  int i=blockIdx.x*256+threadIdx.x;
  if(i>=N_) return;
  int4 c=coords[i];
  int lin=(c.y*H_+c.z)*W_+c.w;
  uint32_t s=hash0(lin);
  for(;;){
    int old=atomicCAS(&h[s].x,-1,lin);
    if(old==-1){ h[s].y=i; break; }
    s=(s+1)&HMASK;
  }
}

// =================================================================
// MAIN F32 PATH: k-grouped pair lists + register-resident weights
// =================================================================

// wave-aggregated list append (one atomic per wave per tap; counter padded)
__device__ __forceinline__ void wappend(int2* __restrict__ lst,int* __restrict__ cnt,
                                        int cap,int a,int b,bool want,int lane){
  unsigned long long m=__ballot(want);
  if(m==0ull) return;
  int first=__builtin_ctzll(m);
  int base=0;
  if(lane==first) base=atomicAdd(cnt,__popcll(m));
  base=__shfl(base,first);
  if(want){
    int pref=__popcll(m&((1ull<<lane)-1ull));
    int pos=base+pref;
    if(pos<cap) lst[pos]=make_int2(a,b);
  }
}

// conv pair lists for both offset patterns; tap order staggered per block so
// concurrent atomics spread across all (padded) counter lines.
__global__ __launch_bounds__(256)
void k_build_conv(const int4* __restrict__ coords,const int* __restrict__ table,
                  int2* __restrict__ listA,int2* __restrict__ listB,
                  int* __restrict__ cntA,int* __restrict__ cntB,
                  const int* __restrict__ flag){
  if(!flag[0]) return;
  int i=blockIdx.x*256+threadIdx.x;
  bool valid=i<N_;
  int4 c = valid? coords[i] : make_int4(0,0,0,0);
  int z=c.y,y=c.z,x=c.w;
  int lane=threadIdx.x&63;
  #pragma unroll
  for(int j=0;j<9;j++){
    int k=(blockIdx.x+j)%9;
    if(k==4) continue;
    int d0=k/3-1, dx=k%3-1;
    { // pattern A (OFF_31): (dz,0,dx)
      int nz=z+d0, nx=x+dx;
      int src=-1;
      if(valid && nz>=0&&nz<D_&&nx>=0&&nx<W_) src=table[(nz*H_+y)*W_+nx];
      wappend(listA+(size_t)k*CAPC,&cntA[k*CSTRIDE],CAPC,i,src,src>=0,lane);
    }
    { // pattern B (OFF_13): (0,dy,dx)
      int ny=y+d0, nx=x+dx;
      int src=-1;
      if(valid && ny>=0&&ny<H_&&nx>=0&&nx<W_) src=table[(z*H_+ny)*W_+nx];
      wappend(listB+(size_t)k*CAPC,&cntB[k*CSTRIDE],CAPC,i,src,src>=0,lane);
    }
  }
}

// pool pair lists; staggered tap order
__global__ __launch_bounds__(256)
void k_build_pool(const int4* __restrict__ coords,int2* __restrict__ listP,
                  int* __restrict__ cntP,const int* __restrict__ flag){
  if(!flag[0]) return;
  int i=blockIdx.x*256+threadIdx.x;
  bool valid=i<N_;
  int4 c = valid? coords[i] : make_int4(0,0,0,0);
  int z=c.y,y=c.z,x=c.w;
  int lane=threadIdx.x&63;
  #pragma unroll
  for(int j=0;j<27;j++){
    int k=(blockIdx.x+j)%27;
    int kd=k/9, kh=(k/3)%3, kw=k%3;
    int tz=z+1-kd, ty=y+1-kh, tx=x+1-kw;
    bool ok = valid && !(tz&1)&&!(ty&1)&&!(tx&1);
    int oz=tz>>1, oy=ty>>1, ox=tx>>1;
    ok = ok && oz>=0&&oz<DO_&&oy>=0&&oy<HO_&&ox>=0&&ox<WO_;
    int cell = ok? ((oz*HO_+oy)*WO_+ox) : -1;
    wappend(listP+(size_t)k*CAPP,&cntP[k*CSTRIDE],CAPP,cell,i,ok,lane);
  }
}

// center tap (k=4): dst row p = act(src row p) @ W[4]; bijection -> plain store.
// __launch_bounds__(256,1): allow full VGPR budget so w[] stays register-resident
// (R4 post-mortem: default bounds forced VGPR=48 -> weight spill, 3x VALU work).
template<int CIN,bool ACT>
__global__ __launch_bounds__(256,1)
void k_center(const float* __restrict__ src,const float* __restrict__ Wl,
              float* __restrict__ dst,const int* __restrict__ flag){
  if(!flag[0]) return;
  int wave=blockIdx.x*4+(threadIdx.x>>6);
  int lane=threadIdx.x&63;
  int p0=wave*4;                        // N_ % 16 == 0 -> exact
  if(p0>=N_) return;
  float w[CIN];
  #pragma unroll
  for(int ci=0;ci<CIN;ci++) w[ci]=Wl[(size_t)4*CIN*64+(size_t)ci*64+lane];
  int li=(CIN==64)? lane : (lane&31);
  float r0=src[(size_t)(p0+0)*CIN+li];
  float r1=src[(size_t)(p0+1)*CIN+li];
  float r2=src[(size_t)(p0+2)*CIN+li];
  float r3=src[(size_t)(p0+3)*CIN+li];
  if(ACT){ r0=lk(r0); r1=lk(r1); r2=lk(r2); r3=lk(r3); }
  float a0=0.f,a1=0.f,a2=0.f,a3=0.f;
  #pragma unroll
  for(int ci=0;ci<CIN;ci++){
    float wc=w[ci];
    a0+=rlane(r0,ci)*wc; a1+=rlane(r1,ci)*wc;
    a2+=rlane(r2,ci)*wc; a3+=rlane(r3,ci)*wc;
  }
  dst[(size_t)(p0+0)*64+lane]=a0;
  dst[(size_t)(p0+1)*64+lane]=a1;
  dst[(size_t)(p0+2)*64+lane]=a2;
  dst[(size_t)(p0+3)*64+lane]=a3;
}

// off-center conv taps: stream (dst,src) pairs of tap g, atomicAdd into dst rows
template<int CIN,bool ACT>
__global__ __launch_bounds__(256,1)
void k_off(const float* __restrict__ src,const float* __restrict__ Wl,
           const int2* __restrict__ lists,const int* __restrict__ cnt,
           float* __restrict__ dst,const int* __restrict__ flag){
  if(!flag[0]) return;
  int g=blockIdx.y;
  if(g==4) return;
  int n=min(cnt[g*CSTRIDE],CAPC);
  const int2* lst=lists+(size_t)g*CAPC;
  int wave=blockIdx.x*4+(threadIdx.x>>6);
  int lane=threadIdx.x&63;
  float w[CIN];
  #pragma unroll
  for(int ci=0;ci<CIN;ci++) w[ci]=Wl[(size_t)g*CIN*64+(size_t)ci*64+lane];
  int nw=gridDim.x*4;
  int li=(CIN==64)? lane : (lane&31);
  for(int p=wave;p<n;p+=nw){
    int2 pr=lst[p];                     // (dst, src)
    float r=src[(size_t)pr.y*CIN+li];
    if(ACT) r=lk(r);
    float a=0.f;
    #pragma unroll
    for(int ci=0;ci<CIN;ci++) a+=rlane(r,ci)*w[ci];
    atomicAdd(&dst[(size_t)pr.x*64+lane],a);
  }
}

// pool stream: tap g weights resident; 4 (cell,voxel) pairs in flight
__global__ __launch_bounds__(256,1)
void k_pools(const float* __restrict__ rAp,const float* __restrict__ Wp,
             const int2* __restrict__ listP,const int* __restrict__ cntP,
             float* __restrict__ out,const int* __restrict__ flag){
  if(!flag[0]) return;
  int g=blockIdx.y;
  int n=min(cntP[g*CSTRIDE],CAPP);
  const int2* lst=listP+(size_t)g*CAPP;
  int wave=blockIdx.x*4+(threadIdx.x>>6);
  int lane=threadIdx.x&63;
  float w[64];
  #pragma unroll
  for(int ci=0;ci<64;ci++) w[ci]=Wp[(size_t)g*4096+(size_t)ci*64+lane];
  int nw=gridDim.x*4;
  for(int p0=wave*4;p0<n;p0+=nw*4){
    int pB=p0+1,pC=p0+2,pD=p0+3;
    bool vB=pB<n, vC=pC<n, vD=pD<n;
    int2 qA=lst[p0];
    int2 qB=vB?lst[pB]:qA;
    int2 qC=vC?lst[pC]:qA;
    int2 qD=vD?lst[pD]:qA;
    float rA_=rAp[(size_t)qA.y*64+lane];
    float rB_=rAp[(size_t)qB.y*64+lane];
    float rC_=rAp[(size_t)qC.y*64+lane];
    float rD_=rAp[(size_t)qD.y*64+lane];
    float aA=0.f,aB=0.f,aC=0.f,aD=0.f;
    #pragma unroll
    for(int ci=0;ci<64;ci++){
      float wc=w[ci];
      aA+=rlane(rA_,ci)*wc;
      aB+=rlane(rB_,ci)*wc;
      aC+=rlane(rC_,ci)*wc;
      aD+=rlane(rD_,ci)*wc;
    }
    atomicAdd(&out[(size_t)qA.x*64+lane],aA);
    if(vB) atomicAdd(&out[(size_t)qB.x*64+lane],aB);
    if(vC) atomicAdd(&out[(size_t)qC.x*64+lane],aC);
    if(vD) atomicAdd(&out[(size_t)qD.x*64+lane],aD);
  }
}

// rA = leaky(raw L4) + leaky(raw sc)   (both activations fused here)
__global__ __launch_bounds__(256)
void k_act_resid(float* __restrict__ r,const float* __restrict__ sc,
                 const int* __restrict__ flag){
  if(!flag[0]) return;
  size_t n=(size_t)N_*64;
  size_t stride=(size_t)gridDim.x*1024;
  for(size_t i=((size_t)blockIdx.x*256+threadIdx.x)*4;i<n;i+=stride){
    float4 v=*(float4*)(r+i);
    float4 s=*(const float4*)(sc+i);
    v.x=lk(v.x)+lk(s.x); v.y=lk(v.y)+lk(s.y);
    v.z=lk(v.z)+lk(s.z); v.w=lk(v.w)+lk(s.w);
    *(float4*)(r+i)=v;
  }
}
__global__ __launch_bounds__(256)
void k_zero(float* __restrict__ out,const int* __restrict__ flag){
  if(!flag[0]) return;
  size_t n=(size_t)NCELL*64;
  size_t stride=(size_t)gridDim.x*1024;
  float4 z=make_float4(0.f,0.f,0.f,0.f);
  for(size_t i=((size_t)blockIdx.x*256+threadIdx.x)*4;i<n;i+=stride)
    *(float4*)(out+i)=z;
}

// =================================================================
// BF16 MAIN PATH (flag==0): verified R1 gather kernels, bufs in ob scratch
// =================================================================
template<int CIN,bool AXIS31,int SRC,int DST,bool RESID>
__global__ __launch_bounds__(256)
void k_convb(const void* __restrict__ feats,const int4* __restrict__ coords,
             const int* __restrict__ table,const void* __restrict__ Wk,
             char* __restrict__ ob,const int* __restrict__ flag){
  if(flag[0]) return;
  uint16_t* buf0=(uint16_t*)ob;
  uint16_t* buf1=buf0+(size_t)N_*64;
  int wave=blockIdx.x*4+(threadIdx.x>>6);
  int lane=threadIdx.x&63;
  if(wave>=N_) return;
  int4 c=coords[wave];
  int z=c.y,y=c.z,x=c.w;
  int nidx=-1;
  if(lane<9){
    int d0=lane/3-1, dxo=lane%3-1;
    int nz=AXIS31? z+d0:z;
    int ny=AXIS31? y:y+d0;
    int nx=x+dxo;
    if(nz>=0&&nz<D_&&ny>=0&&ny<H_&&nx>=0&&nx<W_)
      nidx=table[(nz*H_+ny)*W_+nx];
  }
  unsigned long long m=__ballot(nidx>=0);
  float acc=0.f;
  while(m){
    int k=__builtin_ctzll(m); m&=m-1;
    int idx=__shfl(nidx,k);
    size_t fb=(size_t)idx*CIN;
    size_t wb=(size_t)k*CIN*64+lane;
    #pragma unroll
    for(int g=0;g<CIN/8;g++){
      float f[8];
      if(SRC==0) ld8<false>(feats,fb+(size_t)8*g,f);
      else       ld8<false>(buf0 ,fb+(size_t)8*g,f);
      #pragma unroll
      for(int j=0;j<8;j++)
        acc+=f[j]*ldv<false>(Wk,wb+(size_t)(8*g+j)*64);
    }
  }
  float v=acc>0.f? acc:0.01f*acc;
  if(RESID) v+=bf2f(buf1[(size_t)wave*64+lane]);
  size_t oi=(size_t)wave*64+lane;
  if(DST==0)      buf0[oi]=f2bf(v);
  else if(DST==1) buf1[oi]=f2bf(v);
  else            stv<false>(ob+(size_t)NCELL*64*2,oi,v);
}

__global__ __launch_bounds__(256)
void k_poolb(const int* __restrict__ table,const void* __restrict__ Wp,
             char* __restrict__ ob,const int* __restrict__ flag){
  if(flag[0]) return;
  const char* rAp=ob+(size_t)NCELL*64*2;
  int wave=blockIdx.x*4+(threadIdx.x>>6);
  int lane=threadIdx.x&63;
  int cell0=wave*2;
  if(cell0>=NCELL) return;
  int half=lane>>5, l=lane&31;
  int cell=cell0+half;
  int ox=cell&(WO_-1);
  int t=cell>>4;
  int oy=t%HO_, oz=t/HO_;
  int nidx=-1;
  if(l<27){
    int kd=l/9, kh=(l/3)%3, kw=l%3;
    int z=2*oz+kd-1, y=2*oy+kh-1, x=2*ox+kw-1;
    if(z>=0&&z<D_&&y>=0&&y<H_&&x>=0&&x<W_)
      nidx=table[(z*H_+y)*W_+x];
  }
  unsigned long long m=__ballot(nidx>=0);
  unsigned int ma=(unsigned int)(m&0x07FFFFFFull);
  unsigned int mb=(unsigned int)((m>>32)&0x07FFFFFFull);
  float acc0=0.f, acc1=0.f;
  while(ma|mb){
    int ka=-1,kb=-1,ia=0,ib=0;
    if(ma){ ka=__builtin_ctz(ma); ma&=ma-1; ia=__shfl(nidx,ka); }
    if(mb){ kb=__builtin_ctz(mb); mb&=mb-1; ib=__shfl(nidx,32+kb); }
    if(ka>=0){
      size_t fb=(size_t)ia*64, wb=(size_t)ka*4096+lane;
      #pragma unroll
      for(int g=0;g<8;g++){
        float f[8]; ld8<false>(rAp,fb+(size_t)8*g,f);
        #pragma unroll
        for(int j=0;j<8;j++) acc0+=f[j]*ldv<false>(Wp,wb+(size_t)(8*g+j)*64);
      }
    }
    if(kb>=0){
      size_t fb=(size_t)ib*64, wb=(size_t)kb*4096+lane;
      #pragma unroll
      for(int g=0;g<8;g++){
        float f[8]; ld8<false>(rAp,fb+(size_t)8*g,f);
        #pragma unroll
        for(int j=0;j<8;j++) acc1+=f[j]*ldv<false>(Wp,wb+(size_t)(8*g+j)*64);
      }
    }
  }
  stv<false>(ob,(size_t)cell0*64+lane,acc0);
  stv<false>(ob,((size_t)cell0+1)*64+lane,acc1);
}

// =================================================================
// FALLBACK PATH (ws too small): legacy hash-based kernels, unchanged
// =================================================================
template<int CIN,bool AXIS31,int SRC,int DST,bool RESID,bool F32>
__device__ __forceinline__ void conv_body(const void* __restrict__ feats,
                                          const int4* __restrict__ coords,
                                          const int2* __restrict__ hash,
                                          const void* __restrict__ Wk,
                                          char* __restrict__ ob){
  constexpr size_t ESZ=F32?4:2;
  uint16_t* buf0=(uint16_t*)(ob+(size_t)PBZ_CELLS*64*ESZ);
  uint16_t* buf1=buf0+(size_t)N_*64;
  int wave=blockIdx.x*4+(threadIdx.x>>6);
  int lane=threadIdx.x&63;
  if(wave>=N_) return;
  int4 c=coords[wave];
  int z=c.y,y=c.z,x=c.w;
  float acc=0.f;
  #pragma unroll
  for(int k=0;k<9;k++){
    const int d0=k/3-1, dxo=k%3-1;
    int nz=AXIS31? z+d0:z;
    int ny=AXIS31? y:y+d0;
    int nx=x+dxo;
    int nidx=-1;
    if(nz>=0&&nz<D_&&ny>=0&&ny<H_&&nx>=0&&nx<W_)
      nidx=hlookup(hash,(nz*H_+ny)*W_+nx);
    nidx=__builtin_amdgcn_readfirstlane(nidx);
    if(nidx<0) continue;
    size_t fb=(size_t)nidx*CIN;
    size_t wb=(size_t)k*CIN*64+lane;
    #pragma unroll
    for(int ci=0;ci<CIN;ci+=2){
      float f0=(SRC==0)? ldv<F32>(feats,fb+ci)   : bf2f(buf0[fb+ci]);
      float f1=(SRC==0)? ldv<F32>(feats,fb+ci+1) : bf2f(buf0[fb+ci+1]);
      acc += f0*ldv<F32>(Wk,wb+(size_t)ci*64);
      acc += f1*ldv<F32>(Wk,wb+(size_t)(ci+1)*64);
    }
  }
  float v=acc>0.f? acc:0.01f*acc;
  if(RESID) v+=bf2f(buf1[(size_t)wave*64+lane]);
  size_t oi=(size_t)wave*64+lane;
  if(DST==0)      buf0[oi]=f2bf(v);
  else if(DST==1) buf1[oi]=f2bf(v);
  else            stv<F32>(ob+(size_t)NCELL*64*ESZ,oi,v);
}
template<int CIN,bool AXIS31,int SRC,int DST,bool RESID>
__global__ __launch_bounds__(256)
void k_conv(const void* feats,const int4* coords,const int2* hash,const void* Wk,
            char* ob,const int* flag){
  if(flag[0]) conv_body<CIN,AXIS31,SRC,DST,RESID,true >(feats,coords,hash,Wk,ob);
  else        conv_body<CIN,AXIS31,SRC,DST,RESID,false>(feats,coords,hash,Wk,ob);
}
template<bool F32>
__device__ __forceinline__ float pool_cell_t(int cell,const void* __restrict__ rA,
    const int2* __restrict__ hash,const void* __restrict__ Wp,int lane){
  int ox=cell&(WO_-1);
  int t=cell>>4;
  int oy=t%HO_, oz=t/HO_;
  float acc=0.f;
  int k=0;
  for(int kd=0;kd<3;kd++)for(int kh=0;kh<3;kh++)for(int kw=0;kw<3;kw++,k++){
    int z=2*oz+kd-1, y=2*oy+kh-1, x=2*ox+kw-1;
    if(z<0||z>=D_||y<0||y>=H_||x<0||x>=W_) continue;
    int nidx=hlookup(hash,(z*H_+y)*W_+x);
    nidx=__builtin_amdgcn_readfirstlane(nidx);
    if(nidx<0) continue;
    size_t fb=(size_t)nidx*64;
    size_t wb=(size_t)k*4096+lane;
    #pragma unroll
    for(int ci=0;ci<64;ci+=2){
      acc+=ldv<F32>(rA,fb+ci)  *ldv<F32>(Wp,wb+(size_t)ci*64);
      acc+=ldv<F32>(rA,fb+ci+1)*ldv<F32>(Wp,wb+(size_t)(ci+1)*64);
    }
  }
  return acc;
}
template<bool F32>
__device__ __forceinline__ void pool_fb_body(const void* __restrict__ Wp,
                                             char* __restrict__ ob,
                                             int* __restrict__ cnt){
  constexpr size_t ESZ=F32?4:2;
  const int2* hash=(const int2*)ob;
  const void* rA=ob+(size_t)NCELL*64*ESZ;
  int w=blockIdx.x*4+(threadIdx.x>>6);
  int lane=threadIdx.x&63;
  for(int cell=PBZ_CELLS+w; cell<NCELL; cell+=POOL_WAVES)
    stv<F32>(ob,(size_t)cell*64+lane, pool_cell_t<F32>(cell,rA,hash,Wp,lane));
  float accb[PB_PER_WAVE];
  #pragma unroll
  for(int j=0;j<PB_PER_WAVE;j++)
    accb[j]=pool_cell_t<F32>(w*PB_PER_WAVE+j,rA,hash,Wp,lane);
  __syncthreads();
  if(threadIdx.x==0){
    __threadfence();
    atomicAdd(cnt,1);
    while(atomicAdd(cnt,0)<POOL_BLOCKS) __builtin_amdgcn_s_sleep(8);
  }
  __syncthreads();
  #pragma unroll
  for(int j=0;j<PB_PER_WAVE;j++)
    stv<F32>(ob,(size_t)(w*PB_PER_WAVE+j)*64+lane,accb[j]);
}
__global__ __launch_bounds__(256,2)
void k_pool_fb(const void* Wp,char* ob,int* cnt,const int* flag){
  if(flag[0]) pool_fb_body<true >(Wp,ob,cnt);
  else        pool_fb_body<false>(Wp,ob,cnt);
}

extern "C" void kernel_launch(void* const* d_in,const int* in_sizes,int n_in,
                              void* d_out,int out_size,void* d_ws,size_t ws_size,
                              hipStream_t stream){
  const uint16_t* feats_u16=(const uint16_t*)d_in[0];
  const void* feats=d_in[0];
  const int4* coords=(const int4*)d_in[1];
  const void* W1  =d_in[2];
  const void* W1_2=d_in[3];
  const void* W2  =d_in[4];
  const void* W3  =d_in[5];
  const void* Wp  =d_in[6];
  char* ob=(char*)d_out;
  int* flag=(int*)d_ws;            // [0]=dtype, [1]=barrier, counters at +512B

  // ws layout (main path):
  //   [0,512)        flags
  //   [512, 6272)    45 padded counters (128 B each)
  //   8192           dense table         22.1 MB
  //   +              listA (9*CAPC int2)  1.2 MB
  //   +              listB (9*CAPC int2)  1.2 MB
  //   +              listP (27*CAPP int2) 7.1 MB  => ~31.6 MB total
  const size_t OFF_TABLE=8192;
  const size_t OFF_LISTA=OFF_TABLE+(size_t)NVOX*4;
  const size_t OFF_LISTB=OFF_LISTA+(size_t)9*CAPC*8;
  const size_t OFF_LISTP=OFF_LISTB+(size_t)9*CAPC*8;
  const size_t WS_NEED  =OFF_LISTP+(size_t)27*CAPP*8;
  const bool ws_ok = ws_size >= WS_NEED;

  int* cnt =flag+128;              // padded: counter t at cnt[t*CSTRIDE]
  int* cntA=cnt, *cntB=cnt+9*CSTRIDE, *cntP=cnt+18*CSTRIDE;
  int*  table=(int*)((char*)d_ws+OFF_TABLE);
  int2* listA=(int2*)((char*)d_ws+OFF_LISTA);
  int2* listB=(int2*)((char*)d_ws+OFF_LISTB);
  int2* listP=(int2*)((char*)d_ws+OFF_LISTP);

  // f32-mode buffers carved from d_out's pooled region (dead until pool):
  float* bufA=(float*)ob;                          // 51.2 MB
  float* bufB=(float*)(ob+(size_t)N_*64*4);        // 51.2 MB (ends at 102.4 < 176.9)
  float* rAf =(float*)(ob+(size_t)NCELL*64*4);     // final rA region (f32 mode)

  k_sniff<<<1,256,0,stream>>>(feats_u16,flag);

  if(ws_ok){
    k_table_init <<<NVOX/4/256,256,0,stream>>>(table);
    k_table_build<<<(N_+255)/256,256,0,stream>>>(coords,table);
    k_build_conv <<<(N_+255)/256,256,0,stream>>>(coords,table,listA,listB,cntA,cntB,flag);
    k_build_pool <<<(N_+255)/256,256,0,stream>>>(coords,listP,cntP,flag);

    const float* W1f  =(const float*)W1;
    const float* W12f =(const float*)W1_2;
    const float* W2f  =(const float*)W2;
    const float* W3f  =(const float*)W3;
    const float* Wpf  =(const float*)Wp;
    const float* featsf=(const float*)feats;

    // L1: raw1 = subm(feats, W1, OFF_31) -> bufA   (act fused into L2 reads)
    k_center<32,false><<<N_/16,256,0,stream>>>(featsf,W1f,bufA,flag);
    k_off<32,false><<<dim3(64,9),256,0,stream>>>(featsf,W1f,listA,cntA,bufA,flag);
    // L2: raw_sc = subm(lk(raw1), W1_2, OFF_13) -> bufB (act fused into resid)
    k_center<64,true ><<<N_/16,256,0,stream>>>(bufA,W12f,bufB,flag);
    k_off<64,true ><<<dim3(64,9),256,0,stream>>>(bufA,W12f,listB,cntB,bufB,flag);
    // L3: raw2 = subm(feats, W2, OFF_13) -> bufA   (act fused into L4 reads)
    k_center<32,false><<<N_/16,256,0,stream>>>(featsf,W2f,bufA,flag);
    k_off<32,false><<<dim3(64,9),256,0,stream>>>(featsf,W2f,listB,cntB,bufA,flag);
    // L4: raw3 = subm(lk(raw2), W3, OFF_31) -> rAf
    k_center<64,true ><<<N_/16,256,0,stream>>>(bufA,W3f,rAf,flag);
    k_off<64,true ><<<dim3(64,9),256,0,stream>>>(bufA,W3f,listA,cntA,rAf,flag);
    // rA = lk(raw3) + lk(raw_sc)
    k_act_resid<<<2048,256,0,stream>>>(rAf,bufB,flag);
    // pool: zero output (bufs dead), scatter-add streams
    k_zero<<<4096,256,0,stream>>>((float*)ob,flag);
    k_pools<<<dim3(128,27),256,0,stream>>>(rAf,Wpf,listP,cntP,(float*)ob,flag);

    // bf16-mode path (no-ops when flag[0]==1)
    k_convb<32,true ,0,0,false><<<N_/4,256,0,stream>>>(feats,coords,table,W1  ,ob,flag);
    k_convb<64,false,1,1,false><<<N_/4,256,0,stream>>>(feats,coords,table,W1_2,ob,flag);
    k_convb<32,false,0,0,false><<<N_/4,256,0,stream>>>(feats,coords,table,W2  ,ob,flag);
    k_convb<64,true ,1,2,true ><<<N_/4,256,0,stream>>>(feats,coords,table,W3  ,ob,flag);
    k_poolb<<<NCELL/8,256,0,stream>>>(table,Wp,ob,flag);
  }else{
    int2* hash=(int2*)ob;
    k_hash_init<<<(HSZ+255)/256,256,0,stream>>>(hash);
    k_hash_build<<<(N_+255)/256,256,0,stream>>>(coords,hash);
    k_conv<32,true ,0,0,false><<<N_/4,256,0,stream>>>(feats,coords,hash,W1  ,ob,flag);
    k_conv<64,false,1,1,false><<<N_/4,256,0,stream>>>(feats,coords,hash,W1_2,ob,flag);
    k_conv<32,false,0,0,false><<<N_/4,256,0,stream>>>(feats,coords,hash,W2  ,ob,flag);
    k_conv<64,true ,1,2,true ><<<N_/4,256,0,stream>>>(feats,coords,hash,W3  ,ob,flag);
    k_pool_fb<<<POOL_BLOCKS,256,0,stream>>>(Wp,ob,flag+1,flag);
  }
}

// Round 6
// 912.300 us; speedup vs baseline: 3.1124x; 1.0500x over previous
//
#include <hip/hip_runtime.h>
#include <stdint.h>

#define D_  480
#define H_  360
#define W_  32
#define N_  200000
#define DO_ 240
#define HO_ 180
#define WO_ 16
#define NCELL (DO_*HO_*WO_)     // 691,200
#define NVOX  (D_*H_*W_)        // 5,529,600
#define HBITS 19
#define HSZ   (1<<HBITS)
#define HMASK (HSZ-1)
#define CAPC 16384              // per off-center conv tap (expect ~7.2k)
#define CAPP 32768              // per pool tap (expect ~25k)
#define CSTRIDE 32              // counter padding: 32 ints = 128 B per counter

// fallback persistent pool constants
#define PBZ_CELLS 32768
#define POOL_BLOCKS 512
#define POOL_WAVES (POOL_BLOCKS*4)
#define PB_PER_WAVE (PBZ_CELLS/POOL_WAVES)   // 16

typedef float f32x16 __attribute__((ext_vector_type(16)));

__device__ __forceinline__ float bf2f(uint16_t u){
  uint32_t x=((uint32_t)u)<<16; return __builtin_bit_cast(float,x);
}
__device__ __forceinline__ uint16_t f2bf(float f){
  uint32_t x=__builtin_bit_cast(uint32_t,f);
  uint32_t r=x+0x7fffu+((x>>16)&1u);          // RNE
  return (uint16_t)(r>>16);
}
template<bool F32> __device__ __forceinline__ float ldv(const void* p,size_t i){
  if constexpr(F32) return ((const float*)p)[i];
  else return bf2f(((const uint16_t*)p)[i]);
}
template<bool F32> __device__ __forceinline__ void stv(void* p,size_t i,float v){
  if constexpr(F32) ((float*)p)[i]=v;
  else ((uint16_t*)p)[i]=f2bf(v);
}
// broadcast-load 8 consecutive values -> f32[8] (bf16 path)
template<bool F32> __device__ __forceinline__ void ld8(const void* p,size_t base,float* v){
  if constexpr(F32){
    const float4* q=(const float4*)((const float*)p+base);
    float4 a=q[0], b=q[1];
    v[0]=a.x;v[1]=a.y;v[2]=a.z;v[3]=a.w;
    v[4]=b.x;v[5]=b.y;v[6]=b.z;v[7]=b.w;
  }else{
    const uint4* q=(const uint4*)((const uint16_t*)p+base);
    uint4 a=q[0];
    v[0]=bf2f((uint16_t)(a.x&0xffffu)); v[1]=bf2f((uint16_t)(a.x>>16));
    v[2]=bf2f((uint16_t)(a.y&0xffffu)); v[3]=bf2f((uint16_t)(a.y>>16));
    v[4]=bf2f((uint16_t)(a.z&0xffffu)); v[5]=bf2f((uint16_t)(a.z>>16));
    v[6]=bf2f((uint16_t)(a.w&0xffffu)); v[7]=bf2f((uint16_t)(a.w>>16));
  }
}
// register-file broadcast (lane index is a literal after unrolling)
__device__ __forceinline__ float rlane(float v,int l){
  return __builtin_bit_cast(float,
      __builtin_amdgcn_readlane(__builtin_bit_cast(int,v),l));
}
__device__ __forceinline__ float lk(float v){ return v>0.f? v:0.01f*v; }

// ---- register-resident weight column: ext_vector SSA values (rule #20 fix) ----
template<int CIN> struct WR { f32x16 v[CIN/16]; };
template<int CIN>
__device__ __forceinline__ void wload(WR<CIN>& w,const float* __restrict__ Wt,int lane){
  #pragma unroll
  for(int j=0;j<CIN/16;j++)
    #pragma unroll
    for(int i=0;i<16;i++)
      w.v[j][i]=Wt[(size_t)(j*16+i)*64+lane];
}
// R rows in parallel; FP order per-row: ci strictly ascending (matches prior pass)
template<int CIN,int R>
__device__ __forceinline__ void wdotR(float* a,const float* r,const WR<CIN>& w){
  #pragma unroll
  for(int j=0;j<CIN/16;j++)
    #pragma unroll
    for(int i=0;i<16;i++){
      float wc=w.v[j][i];
      #pragma unroll
      for(int q=0;q<R;q++) a[q]+=rlane(r[q],j*16+i)*wc;
    }
}

__device__ __forceinline__ uint32_t hash0(int lin){
  return ((uint32_t)((uint32_t)lin*2654435761u)>>12)&HMASK;
}
__device__ __forceinline__ int hlookup(const int2* __restrict__ h,int lin){
  uint32_t s=hash0(lin);
  for(;;){ int2 kv=h[s]; if(kv.x==lin) return kv.y; if(kv.x<0) return -1; s=(s+1)&HMASK; }
}

// dtype sniff: flag[0]=1 iff inputs are f32. Zeroes flag[1] + 45 PADDED counters.
__global__ void k_sniff(const uint16_t* __restrict__ feats,int* __restrict__ flag){
  __shared__ int s;
  if(threadIdx.x==0) s=0;
  __syncthreads();
  int bad=0;
  for(int i=threadIdx.x;i<512;i+=256){
    int e=(feats[i]>>7)&0xff;
    bad += (e>=0x90)?1:0;
  }
  atomicAdd(&s,bad);
  if(threadIdx.x<45) flag[128+threadIdx.x*CSTRIDE]=0;
  __syncthreads();
  if(threadIdx.x==0){ flag[0]=(s>=8)?1:0; flag[1]=0; }
}

// ---------------- dense direct-index voxel table (lives in ws) ----------------
__global__ void k_table_init(int* __restrict__ t){
  int i=blockIdx.x*256+threadIdx.x;
  if(i<NVOX/4) ((int4*)t)[i]=make_int4(-1,-1,-1,-1);
}
__global__ void k_table_build(const int4* __restrict__ coords,int* __restrict__ t){
  int i=blockIdx.x*256+threadIdx.x;
  if(i>=N_) return;
  int4 c=coords[i];                      // (b,z,y,x), b==0
  t[(c.y*H_+c.z)*W_+c.w]=i;
}

// ---------------- legacy hash (fallback path only) ----------------
__global__ void k_hash_init(int2* __restrict__ h){
  int i=blockIdx.x*256+threadIdx.x;
  if(i<HSZ) h[i]=make_int2(-1,-1);
}
__global__ void k_hash_build(const int4* __restrict__ coords,int2* __restrict__ h){
  int i=blockIdx.x*256+threadIdx.x;
  if(i>=N_) return;
  int4 c=coords[i];
  int lin=(c.y*H_+c.z)*W_+c.w;
  uint32_t s=hash0(lin);
  for(;;){
    int old=atomicCAS(&h[s].x,-1,lin);
    if(old==-1){ h[s].y=i; break; }
    s=(s+1)&HMASK;
  }
}

// =================================================================
// MAIN F32 PATH: k-grouped pair lists + register-resident weights
// =================================================================

// wave-aggregated list append (one atomic per wave per tap; counter padded)
__device__ __forceinline__ void wappend(int2* __restrict__ lst,int* __restrict__ cnt,
                                        int cap,int a,int b,bool want,int lane){
  unsigned long long m=__ballot(want);
  if(m==0ull) return;
  int first=__builtin_ctzll(m);
  int base=0;
  if(lane==first) base=atomicAdd(cnt,__popcll(m));
  base=__shfl(base,first);
  if(want){
    int pref=__popcll(m&((1ull<<lane)-1ull));
    int pos=base+pref;
    if(pos<cap) lst[pos]=make_int2(a,b);
  }
}

// fused pair-list build: conv A/B patterns + pool taps, one coords read.
// Tap order staggered per block so concurrent atomics spread across counter lines.
__global__ __launch_bounds__(256)
void k_build(const int4* __restrict__ coords,const int* __restrict__ table,
             int2* __restrict__ listA,int2* __restrict__ listB,
             int2* __restrict__ listP,
             int* __restrict__ cntA,int* __restrict__ cntB,int* __restrict__ cntP,
             const int* __restrict__ flag){
  if(!flag[0]) return;
  int i=blockIdx.x*256+threadIdx.x;
  bool valid=i<N_;
  int4 c = valid? coords[i] : make_int4(0,0,0,0);
  int z=c.y,y=c.z,x=c.w;
  int lane=threadIdx.x&63;
  #pragma unroll
  for(int j=0;j<9;j++){
    int k=(blockIdx.x+j)%9;
    if(k==4) continue;
    int d0=k/3-1, dx=k%3-1;
    { // pattern A (OFF_31): (dz,0,dx)
      int nz=z+d0, nx=x+dx;
      int src=-1;
      if(valid && nz>=0&&nz<D_&&nx>=0&&nx<W_) src=table[(nz*H_+y)*W_+nx];
      wappend(listA+(size_t)k*CAPC,&cntA[k*CSTRIDE],CAPC,i,src,src>=0,lane);
    }
    { // pattern B (OFF_13): (0,dy,dx)
      int ny=y+d0, nx=x+dx;
      int src=-1;
      if(valid && ny>=0&&ny<H_&&nx>=0&&nx<W_) src=table[(z*H_+ny)*W_+nx];
      wappend(listB+(size_t)k*CAPC,&cntB[k*CSTRIDE],CAPC,i,src,src>=0,lane);
    }
  }
  #pragma unroll
  for(int j=0;j<27;j++){
    int k=(blockIdx.x+j)%27;
    int kd=k/9, kh=(k/3)%3, kw=k%3;
    int tz=z+1-kd, ty=y+1-kh, tx=x+1-kw;
    bool ok = valid && !(tz&1)&&!(ty&1)&&!(tx&1);
    int oz=tz>>1, oy=ty>>1, ox=tx>>1;
    ok = ok && oz>=0&&oz<DO_&&oy>=0&&oy<HO_&&ox>=0&&ox<WO_;
    int cell = ok? ((oz*HO_+oy)*WO_+ox) : -1;
    wappend(listP+(size_t)k*CAPP,&cntP[k*CSTRIDE],CAPP,cell,i,ok,lane);
  }
}

// center tap (k=4): dst row p = act(src row p) @ W[4]; bijection -> plain store.
// 8 rows per wave; weights in f32x16 SSA registers.
template<int CIN,bool ACT>
__global__ __launch_bounds__(256,1)
void k_center(const float* __restrict__ src,const float* __restrict__ Wl,
              float* __restrict__ dst,const int* __restrict__ flag){
  if(!flag[0]) return;
  int wave=blockIdx.x*4+(threadIdx.x>>6);
  int lane=threadIdx.x&63;
  int p0=wave*8;                        // N_ % 32 == 0 -> exact
  if(p0>=N_) return;
  WR<CIN> w;
  wload<CIN>(w,Wl+(size_t)4*CIN*64,lane);
  int li=(CIN==64)? lane : (lane&31);
  float r[8],a[8];
  #pragma unroll
  for(int q=0;q<8;q++){
    r[q]=src[(size_t)(p0+q)*CIN+li];
    if(ACT) r[q]=lk(r[q]);
    a[q]=0.f;
  }
  wdotR<CIN,8>(a,r,w);
  #pragma unroll
  for(int q=0;q<8;q++) dst[(size_t)(p0+q)*64+lane]=a[q];
}

// off-center conv taps: stream (dst,src) pairs of tap g, 2 pairs in flight
template<int CIN,bool ACT>
__global__ __launch_bounds__(256,1)
void k_off(const float* __restrict__ src,const float* __restrict__ Wl,
           const int2* __restrict__ lists,const int* __restrict__ cnt,
           float* __restrict__ dst,const int* __restrict__ flag){
  if(!flag[0]) return;
  int g=blockIdx.y;
  if(g==4) return;
  int n=min(cnt[g*CSTRIDE],CAPC);
  const int2* lst=lists+(size_t)g*CAPC;
  int wave=blockIdx.x*4+(threadIdx.x>>6);
  int lane=threadIdx.x&63;
  WR<CIN> w;
  wload<CIN>(w,Wl+(size_t)g*CIN*64,lane);
  int nw=gridDim.x*4;
  int li=(CIN==64)? lane : (lane&31);
  for(int p0=wave*2;p0<n;p0+=nw*2){
    int p1=p0+1;
    bool v1=p1<n;
    int2 qA=lst[p0];
    int2 qB=v1?lst[p1]:qA;
    float r[2],a[2];
    r[0]=src[(size_t)qA.y*CIN+li];
    r[1]=src[(size_t)qB.y*CIN+li];
    if(ACT){ r[0]=lk(r[0]); r[1]=lk(r[1]); }
    a[0]=0.f; a[1]=0.f;
    wdotR<CIN,2>(a,r,w);
    atomicAdd(&dst[(size_t)qA.x*64+lane],a[0]);
    if(v1) atomicAdd(&dst[(size_t)qB.x*64+lane],a[1]);
  }
}

// pool stream: tap g weights in registers; 4 (cell,voxel) pairs in flight
__global__ __launch_bounds__(256,1)
void k_pools(const float* __restrict__ rAp,const float* __restrict__ Wp,
             const int2* __restrict__ listP,const int* __restrict__ cntP,
             float* __restrict__ out,const int* __restrict__ flag){
  if(!flag[0]) return;
  int g=blockIdx.y;
  int n=min(cntP[g*CSTRIDE],CAPP);
  const int2* lst=listP+(size_t)g*CAPP;
  int wave=blockIdx.x*4+(threadIdx.x>>6);
  int lane=threadIdx.x&63;
  WR<64> w;
  wload<64>(w,Wp+(size_t)g*4096,lane);
  int nw=gridDim.x*4;
  for(int p0=wave*4;p0<n;p0+=nw*4){
    int pB=p0+1,pC=p0+2,pD=p0+3;
    bool vB=pB<n, vC=pC<n, vD=pD<n;
    int2 qA=lst[p0];
    int2 qB=vB?lst[pB]:qA;
    int2 qC=vC?lst[pC]:qA;
    int2 qD=vD?lst[pD]:qA;
    float r[4],a[4];
    r[0]=rAp[(size_t)qA.y*64+lane];
    r[1]=rAp[(size_t)qB.y*64+lane];
    r[2]=rAp[(size_t)qC.y*64+lane];
    r[3]=rAp[(size_t)qD.y*64+lane];
    a[0]=0.f;a[1]=0.f;a[2]=0.f;a[3]=0.f;
    wdotR<64,4>(a,r,w);
    atomicAdd(&out[(size_t)qA.x*64+lane],a[0]);
    if(vB) atomicAdd(&out[(size_t)qB.x*64+lane],a[1]);
    if(vC) atomicAdd(&out[(size_t)qC.x*64+lane],a[2]);
    if(vD) atomicAdd(&out[(size_t)qD.x*64+lane],a[3]);
  }
}

// rA = leaky(raw L4) + leaky(raw sc)   (both activations fused here)
__global__ __launch_bounds__(256)
void k_act_resid(float* __restrict__ r,const float* __restrict__ sc,
                 const int* __restrict__ flag){
  if(!flag[0]) return;
  size_t n=(size_t)N_*64;
  size_t stride=(size_t)gridDim.x*1024;
  for(size_t i=((size_t)blockIdx.x*256+threadIdx.x)*4;i<n;i+=stride){
    float4 v=*(float4*)(r+i);
    float4 s=*(const float4*)(sc+i);
    v.x=lk(v.x)+lk(s.x); v.y=lk(v.y)+lk(s.y);
    v.z=lk(v.z)+lk(s.z); v.w=lk(v.w)+lk(s.w);
    *(float4*)(r+i)=v;
  }
}

// =================================================================
// BF16 MAIN PATH (flag==0): verified R1 gather kernels, bufs in ob scratch
// =================================================================
template<int CIN,bool AXIS31,int SRC,int DST,bool RESID>
__global__ __launch_bounds__(256)
void k_convb(const void* __restrict__ feats,const int4* __restrict__ coords,
             const int* __restrict__ table,const void* __restrict__ Wk,
             char* __restrict__ ob,const int* __restrict__ flag){
  if(flag[0]) return;
  uint16_t* buf0=(uint16_t*)ob;
  uint16_t* buf1=buf0+(size_t)N_*64;
  int wave=blockIdx.x*4+(threadIdx.x>>6);
  int lane=threadIdx.x&63;
  if(wave>=N_) return;
  int4 c=coords[wave];
  int z=c.y,y=c.z,x=c.w;
  int nidx=-1;
  if(lane<9){
    int d0=lane/3-1, dxo=lane%3-1;
    int nz=AXIS31? z+d0:z;
    int ny=AXIS31? y:y+d0;
    int nx=x+dxo;
    if(nz>=0&&nz<D_&&ny>=0&&ny<H_&&nx>=0&&nx<W_)
      nidx=table[(nz*H_+ny)*W_+nx];
  }
  unsigned long long m=__ballot(nidx>=0);
  float acc=0.f;
  while(m){
    int k=__builtin_ctzll(m); m&=m-1;
    int idx=__shfl(nidx,k);
    size_t fb=(size_t)idx*CIN;
    size_t wb=(size_t)k*CIN*64+lane;
    #pragma unroll
    for(int g=0;g<CIN/8;g++){
      float f[8];
      if(SRC==0) ld8<false>(feats,fb+(size_t)8*g,f);
      else       ld8<false>(buf0 ,fb+(size_t)8*g,f);
      #pragma unroll
      for(int j=0;j<8;j++)
        acc+=f[j]*ldv<false>(Wk,wb+(size_t)(8*g+j)*64);
    }
  }
  float v=acc>0.f? acc:0.01f*acc;
  if(RESID) v+=bf2f(buf1[(size_t)wave*64+lane]);
  size_t oi=(size_t)wave*64+lane;
  if(DST==0)      buf0[oi]=f2bf(v);
  else if(DST==1) buf1[oi]=f2bf(v);
  else            stv<false>(ob+(size_t)NCELL*64*2,oi,v);
}

__global__ __launch_bounds__(256)
void k_poolb(const int* __restrict__ table,const void* __restrict__ Wp,
             char* __restrict__ ob,const int* __restrict__ flag){
  if(flag[0]) return;
  const char* rAp=ob+(size_t)NCELL*64*2;
  int wave=blockIdx.x*4+(threadIdx.x>>6);
  int lane=threadIdx.x&63;
  int cell0=wave*2;
  if(cell0>=NCELL) return;
  int half=lane>>5, l=lane&31;
  int cell=cell0+half;
  int ox=cell&(WO_-1);
  int t=cell>>4;
  int oy=t%HO_, oz=t/HO_;
  int nidx=-1;
  if(l<27){
    int kd=l/9, kh=(l/3)%3, kw=l%3;
    int z=2*oz+kd-1, y=2*oy+kh-1, x=2*ox+kw-1;
    if(z>=0&&z<D_&&y>=0&&y<H_&&x>=0&&x<W_)
      nidx=table[(z*H_+y)*W_+x];
  }
  unsigned long long m=__ballot(nidx>=0);
  unsigned int ma=(unsigned int)(m&0x07FFFFFFull);
  unsigned int mb=(unsigned int)((m>>32)&0x07FFFFFFull);
  float acc0=0.f, acc1=0.f;
  while(ma|mb){
    int ka=-1,kb=-1,ia=0,ib=0;
    if(ma){ ka=__builtin_ctz(ma); ma&=ma-1; ia=__shfl(nidx,ka); }
    if(mb){ kb=__builtin_ctz(mb); mb&=mb-1; ib=__shfl(nidx,32+kb); }
    if(ka>=0){
      size_t fb=(size_t)ia*64, wb=(size_t)ka*4096+lane;
      #pragma unroll
      for(int g=0;g<8;g++){
        float f[8]; ld8<false>(rAp,fb+(size_t)8*g,f);
        #pragma unroll
        for(int j=0;j<8;j++) acc0+=f[j]*ldv<false>(Wp,wb+(size_t)(8*g+j)*64);
      }
    }
    if(kb>=0){
      size_t fb=(size_t)ib*64, wb=(size_t)kb*4096+lane;
      #pragma unroll
      for(int g=0;g<8;g++){
        float f[8]; ld8<false>(rAp,fb+(size_t)8*g,f);
        #pragma unroll
        for(int j=0;j<8;j++) acc1+=f[j]*ldv<false>(Wp,wb+(size_t)(8*g+j)*64);
      }
    }
  }
  stv<false>(ob,(size_t)cell0*64+lane,acc0);
  stv<false>(ob,((size_t)cell0+1)*64+lane,acc1);
}

// =================================================================
// FALLBACK PATH (ws too small): legacy hash-based kernels, unchanged
// =================================================================
template<int CIN,bool AXIS31,int SRC,int DST,bool RESID,bool F32>
__device__ __forceinline__ void conv_body(const void* __restrict__ feats,
                                          const int4* __restrict__ coords,
                                          const int2* __restrict__ hash,
                                          const void* __restrict__ Wk,
                                          char* __restrict__ ob){
  constexpr size_t ESZ=F32?4:2;
  uint16_t* buf0=(uint16_t*)(ob+(size_t)PBZ_CELLS*64*ESZ);
  uint16_t* buf1=buf0+(size_t)N_*64;
  int wave=blockIdx.x*4+(threadIdx.x>>6);
  int lane=threadIdx.x&63;
  if(wave>=N_) return;
  int4 c=coords[wave];
  int z=c.y,y=c.z,x=c.w;
  float acc=0.f;
  #pragma unroll
  for(int k=0;k<9;k++){
    const int d0=k/3-1, dxo=k%3-1;
    int nz=AXIS31? z+d0:z;
    int ny=AXIS31? y:y+d0;
    int nx=x+dxo;
    int nidx=-1;
    if(nz>=0&&nz<D_&&ny>=0&&ny<H_&&nx>=0&&nx<W_)
      nidx=hlookup(hash,(nz*H_+ny)*W_+nx);
    nidx=__builtin_amdgcn_readfirstlane(nidx);
    if(nidx<0) continue;
    size_t fb=(size_t)nidx*CIN;
    size_t wb=(size_t)k*CIN*64+lane;
    #pragma unroll
    for(int ci=0;ci<CIN;ci+=2){
      float f0=(SRC==0)? ldv<F32>(feats,fb+ci)   : bf2f(buf0[fb+ci]);
      float f1=(SRC==0)? ldv<F32>(feats,fb+ci+1) : bf2f(buf0[fb+ci+1]);
      acc += f0*ldv<F32>(Wk,wb+(size_t)ci*64);
      acc += f1*ldv<F32>(Wk,wb+(size_t)(ci+1)*64);
    }
  }
  float v=acc>0.f? acc:0.01f*acc;
  if(RESID) v+=bf2f(buf1[(size_t)wave*64+lane]);
  size_t oi=(size_t)wave*64+lane;
  if(DST==0)      buf0[oi]=f2bf(v);
  else if(DST==1) buf1[oi]=f2bf(v);
  else            stv<F32>(ob+(size_t)NCELL*64*ESZ,oi,v);
}
template<int CIN,bool AXIS31,int SRC,int DST,bool RESID>
__global__ __launch_bounds__(256)
void k_conv(const void* feats,const int4* coords,const int2* hash,const void* Wk,
            char* ob,const int* flag){
  if(flag[0]) conv_body<CIN,AXIS31,SRC,DST,RESID,true >(feats,coords,hash,Wk,ob);
  else        conv_body<CIN,AXIS31,SRC,DST,RESID,false>(feats,coords,hash,Wk,ob);
}
template<bool F32>
__device__ __forceinline__ float pool_cell_t(int cell,const void* __restrict__ rA,
    const int2* __restrict__ hash,const void* __restrict__ Wp,int lane){
  int ox=cell&(WO_-1);
  int t=cell>>4;
  int oy=t%HO_, oz=t/HO_;
  float acc=0.f;
  int k=0;
  for(int kd=0;kd<3;kd++)for(int kh=0;kh<3;kh++)for(int kw=0;kw<3;kw++,k++){
    int z=2*oz+kd-1, y=2*oy+kh-1, x=2*ox+kw-1;
    if(z<0||z>=D_||y<0||y>=H_||x<0||x>=W_) continue;
    int nidx=hlookup(hash,(z*H_+y)*W_+x);
    nidx=__builtin_amdgcn_readfirstlane(nidx);
    if(nidx<0) continue;
    size_t fb=(size_t)nidx*64;
    size_t wb=(size_t)k*4096+lane;
    #pragma unroll
    for(int ci=0;ci<64;ci+=2){
      acc+=ldv<F32>(rA,fb+ci)  *ldv<F32>(Wp,wb+(size_t)ci*64);
      acc+=ldv<F32>(rA,fb+ci+1)*ldv<F32>(Wp,wb+(size_t)(ci+1)*64);
    }
  }
  return acc;
}
template<bool F32>
__device__ __forceinline__ void pool_fb_body(const void* __restrict__ Wp,
                                             char* __restrict__ ob,
                                             int* __restrict__ cnt){
  constexpr size_t ESZ=F32?4:2;
  const int2* hash=(const int2*)ob;
  const void* rA=ob+(size_t)NCELL*64*ESZ;
  int w=blockIdx.x*4+(threadIdx.x>>6);
  int lane=threadIdx.x&63;
  for(int cell=PBZ_CELLS+w; cell<NCELL; cell+=POOL_WAVES)
    stv<F32>(ob,(size_t)cell*64+lane, pool_cell_t<F32>(cell,rA,hash,Wp,lane));
  float accb[PB_PER_WAVE];
  #pragma unroll
  for(int j=0;j<PB_PER_WAVE;j++)
    accb[j]=pool_cell_t<F32>(w*PB_PER_WAVE+j,rA,hash,Wp,lane);
  __syncthreads();
  if(threadIdx.x==0){
    __threadfence();
    atomicAdd(cnt,1);
    while(atomicAdd(cnt,0)<POOL_BLOCKS) __builtin_amdgcn_s_sleep(8);
  }
  __syncthreads();
  #pragma unroll
  for(int j=0;j<PB_PER_WAVE;j++)
    stv<F32>(ob,(size_t)(w*PB_PER_WAVE+j)*64+lane,accb[j]);
}
__global__ __launch_bounds__(256,2)
void k_pool_fb(const void* Wp,char* ob,int* cnt,const int* flag){
  if(flag[0]) pool_fb_body<true >(Wp,ob,cnt);
  else        pool_fb_body<false>(Wp,ob,cnt);
}

extern "C" void kernel_launch(void* const* d_in,const int* in_sizes,int n_in,
                              void* d_out,int out_size,void* d_ws,size_t ws_size,
                              hipStream_t stream){
  const uint16_t* feats_u16=(const uint16_t*)d_in[0];
  const void* feats=d_in[0];
  const int4* coords=(const int4*)d_in[1];
  const void* W1  =d_in[2];
  const void* W1_2=d_in[3];
  const void* W2  =d_in[4];
  const void* W3  =d_in[5];
  const void* Wp  =d_in[6];
  char* ob=(char*)d_out;
  int* flag=(int*)d_ws;            // [0]=dtype, [1]=barrier, counters at +512B

  // host-side dtype gate from byte sizes (skip dead launches when unambiguous)
  const long fbytes=in_sizes? (long)in_sizes[0] : -1;
  const bool h_f32  = fbytes==(long)N_*32*4;
  const bool h_bf16 = fbytes==(long)N_*32*2;
  const bool run_f32  = h_f32  || !(h_f32||h_bf16);
  const bool run_bf16 = h_bf16 || !(h_f32||h_bf16);

  // ws layout (main path):
  //   [0,512)        flags
  //   [512, 6272)    45 padded counters (128 B each)
  //   8192           dense table         22.1 MB
  //   +              listA (9*CAPC int2)  1.2 MB
  //   +              listB (9*CAPC int2)  1.2 MB
  //   +              listP (27*CAPP int2) 7.1 MB  => ~31.6 MB total
  const size_t OFF_TABLE=8192;
  const size_t OFF_LISTA=OFF_TABLE+(size_t)NVOX*4;
  const size_t OFF_LISTB=OFF_LISTA+(size_t)9*CAPC*8;
  const size_t OFF_LISTP=OFF_LISTB+(size_t)9*CAPC*8;
  const size_t WS_NEED  =OFF_LISTP+(size_t)27*CAPP*8;
  const bool ws_ok = ws_size >= WS_NEED;

  int* cnt =flag+128;              // padded: counter t at cnt[t*CSTRIDE]
  int* cntA=cnt, *cntB=cnt+9*CSTRIDE, *cntP=cnt+18*CSTRIDE;
  int*  table=(int*)((char*)d_ws+OFF_TABLE);
  int2* listA=(int2*)((char*)d_ws+OFF_LISTA);
  int2* listB=(int2*)((char*)d_ws+OFF_LISTB);
  int2* listP=(int2*)((char*)d_ws+OFF_LISTP);

  // f32-mode buffers carved from d_out's pooled region (dead until pool):
  float* bufA=(float*)ob;                          // 51.2 MB
  float* bufB=(float*)(ob+(size_t)N_*64*4);        // 51.2 MB (ends at 102.4 < 176.9)
  float* rAf =(float*)(ob+(size_t)NCELL*64*4);     // final rA region (f32 mode)

  k_sniff<<<1,256,0,stream>>>(feats_u16,flag);

  if(ws_ok){
    k_table_init <<<NVOX/4/256,256,0,stream>>>(table);
    k_table_build<<<(N_+255)/256,256,0,stream>>>(coords,table);

    if(run_f32){
      k_build<<<(N_+255)/256,256,0,stream>>>(coords,table,listA,listB,listP,
                                             cntA,cntB,cntP,flag);
      const float* W1f  =(const float*)W1;
      const float* W12f =(const float*)W1_2;
      const float* W2f  =(const float*)W2;
      const float* W3f  =(const float*)W3;
      const float* Wpf  =(const float*)Wp;
      const float* featsf=(const float*)feats;

      // L1: raw1 = subm(feats, W1, OFF_31) -> bufA   (act fused into L2 reads)
      k_center<32,false><<<N_/32,256,0,stream>>>(featsf,W1f,bufA,flag);
      k_off<32,false><<<dim3(64,9),256,0,stream>>>(featsf,W1f,listA,cntA,bufA,flag);
      // L2: raw_sc = subm(lk(raw1), W1_2, OFF_13) -> bufB (act fused into resid)
      k_center<64,true ><<<N_/32,256,0,stream>>>(bufA,W12f,bufB,flag);
      k_off<64,true ><<<dim3(64,9),256,0,stream>>>(bufA,W12f,listB,cntB,bufB,flag);
      // L3: raw2 = subm(feats, W2, OFF_13) -> bufA   (act fused into L4 reads)
      k_center<32,false><<<N_/32,256,0,stream>>>(featsf,W2f,bufA,flag);
      k_off<32,false><<<dim3(64,9),256,0,stream>>>(featsf,W2f,listB,cntB,bufA,flag);
      // L4: raw3 = subm(lk(raw2), W3, OFF_31) -> rAf
      k_center<64,true ><<<N_/32,256,0,stream>>>(bufA,W3f,rAf,flag);
      k_off<64,true ><<<dim3(64,9),256,0,stream>>>(bufA,W3f,listA,cntA,rAf,flag);
      // rA = lk(raw3) + lk(raw_sc)
      k_act_resid<<<2048,256,0,stream>>>(rAf,bufB,flag);
      // pool: zero output (bufs dead), scatter-add streams
      hipMemsetAsync((void*)ob,0,(size_t)NCELL*64*4,stream);
      k_pools<<<dim3(128,27),256,0,stream>>>(rAf,Wpf,listP,cntP,(float*)ob,flag);
    }

    if(run_bf16){
      k_convb<32,true ,0,0,false><<<N_/4,256,0,stream>>>(feats,coords,table,W1  ,ob,flag);
      k_convb<64,false,1,1,false><<<N_/4,256,0,stream>>>(feats,coords,table,W1_2,ob,flag);
      k_convb<32,false,0,0,false><<<N_/4,256,0,stream>>>(feats,coords,table,W2  ,ob,flag);
      k_convb<64,true ,1,2,true ><<<N_/4,256,0,stream>>>(feats,coords,table,W3  ,ob,flag);
      k_poolb<<<NCELL/8,256,0,stream>>>(table,Wp,ob,flag);
    }
  }else{
    int2* hash=(int2*)ob;
    k_hash_init<<<(HSZ+255)/256,256,0,stream>>>(hash);
    k_hash_build<<<(N_+255)/256,256,0,stream>>>(coords,hash);
    k_conv<32,true ,0,0,false><<<N_/4,256,0,stream>>>(feats,coords,hash,W1  ,ob,flag);
    k_conv<64,false,1,1,false><<<N_/4,256,0,stream>>>(feats,coords,hash,W1_2,ob,flag);
    k_conv<32,false,0,0,false><<<N_/4,256,0,stream>>>(feats,coords,hash,W2  ,ob,flag);
    k_conv<64,true ,1,2,true ><<<N_/4,256,0,stream>>>(feats,coords,hash,W3  ,ob,flag);
    k_pool_fb<<<POOL_BLOCKS,256,0,stream>>>(Wp,ob,flag+1,flag);
  }
}